// Round 4
// baseline (454.735 us; speedup 1.0000x reference)
//
#include <hip/hip_runtime.h>
#include <cstdint>
#include <cstddef>

using short8 = __attribute__((ext_vector_type(8))) short;
using f32x4  = __attribute__((ext_vector_type(4))) float;

constexpr int T_ = 1024;
constexpr int N_ = 1024;
constexpr int M_ = 1023;
constexpr int B_ = 4;
constexpr int E_ = 1024;
constexpr int H_ = 16;
constexpr int D_ = 64;

#define MFMA16(a, b, c) __builtin_amdgcn_mfma_f32_16x16x32_bf16((a), (b), (c), 0, 0, 0)

__device__ __forceinline__ unsigned short f2bf(float f) {
    unsigned int u = __float_as_uint(f);
    u += 0x7FFF + ((u >> 16) & 1);          // round-to-nearest-even
    return (unsigned short)(u >> 16);
}
__device__ __forceinline__ float bf2f(unsigned short s) {
    return __uint_as_float(((unsigned int)s) << 16);
}

// global -> LDS direct copy, 16 B per lane. LDS dest must be wave-uniform;
// HW writes lds_base + lane*16.
typedef __attribute__((address_space(1))) const unsigned char gc_byte;
typedef __attribute__((address_space(3))) unsigned char lds_byte;
__device__ __forceinline__ void gload16(const void* g, void* lds) {
    __builtin_amdgcn_global_load_lds((gc_byte*)(uintptr_t)g,
                                     (lds_byte*)(unsigned int)(uintptr_t)lds,
                                     16, 0, 0);
}

// ---------------------------------------------------------------------------
// fp32 -> bf16 conversion, with zero-padding from n..npad (npad % 4 == 0)
// ---------------------------------------------------------------------------
__global__ void f2bf_kernel(const float* __restrict__ src,
                            unsigned short* __restrict__ dst, int n, int npad)
{
    int i = (blockIdx.x * 256 + threadIdx.x) * 4;
    if (i >= npad) return;
    if (i + 4 <= n) {
        const float4 v = *reinterpret_cast<const float4*>(src + i);
        ushort4 o;
        o.x = f2bf(v.x); o.y = f2bf(v.y); o.z = f2bf(v.z); o.w = f2bf(v.w);
        *reinterpret_cast<ushort4*>(dst + i) = o;
    } else {
        for (int k = 0; k < 4; ++k)
            dst[i + k] = (i + k < n) ? f2bf(src[i + k]) : (unsigned short)0;
    }
}

// fp32 -> (bf16 hi, bf16 lo) split.  n % 4 == 0
__global__ void f2bf_hilo_kernel(const float* __restrict__ src,
                                 unsigned short* __restrict__ dhi,
                                 unsigned short* __restrict__ dlo, int n)
{
    int i = (blockIdx.x * 256 + threadIdx.x) * 4;
    if (i >= n) return;
    const float4 v = *reinterpret_cast<const float4*>(src + i);
    float a[4] = {v.x, v.y, v.z, v.w};
    ushort4 hi, lo;
    unsigned short h[4], l[4];
    #pragma unroll
    for (int k = 0; k < 4; ++k) {
        h[k] = f2bf(a[k]);
        l[k] = f2bf(a[k] - bf2f(h[k]));
    }
    hi.x = h[0]; hi.y = h[1]; hi.z = h[2]; hi.w = h[3];
    lo.x = l[0]; lo.y = l[1]; lo.z = l[2]; lo.w = l[3];
    *reinterpret_cast<ushort4*>(dhi + i) = hi;
    *reinterpret_cast<ushort4*>(dlo + i) = lo;
}

// ---------------------------------------------------------------------------
// dw gate kernel (fp32): dw[r*H+h] = sigmoid(node_key_r . dw_w[h] + dw_b[h])
// ---------------------------------------------------------------------------
__global__ void dw_kernel(const float* __restrict__ node_key,
                          const float* __restrict__ dw_w,
                          const float* __restrict__ dw_b,
                          float* __restrict__ dwb)
{
    __shared__ float rowbuf[E_];
    const int r = blockIdx.x;
    const int tid = threadIdx.x;
    for (int idx = tid; idx < E_; idx += 256)
        rowbuf[idx] = node_key[(size_t)r * E_ + idx];
    __syncthreads();
    const int h = tid >> 4;
    const int lane = tid & 15;
    float acc = 0.f;
    const float* wrow = dw_w + (size_t)h * E_;
    for (int k = lane; k < E_; k += 16)
        acc = fmaf(rowbuf[k], wrow[k], acc);
    acc += __shfl_xor(acc, 8);
    acc += __shfl_xor(acc, 4);
    acc += __shfl_xor(acc, 2);
    acc += __shfl_xor(acc, 1);
    if (lane == 0) {
        float x = acc + dw_b[h];
        dwb[(size_t)r * H_ + h] = 1.f / (1.f + __expf(-x));
    }
}

// ---------------------------------------------------------------------------
// Fused input projections (unchanged from R3; see R3 notes).
// ---------------------------------------------------------------------------
__global__ __launch_bounds__(256) void proj_mfma(
    const unsigned short* __restrict__ xq,
    const unsigned short* __restrict__ xk,
    const unsigned short* __restrict__ xn,
    const unsigned short* __restrict__ wbf,
    const float* __restrict__ ipb,
    const float* __restrict__ dwb,
    unsigned short* __restrict__ qb,
    unsigned short* __restrict__ kb,
    unsigned short* __restrict__ vtb,
    unsigned short* __restrict__ nkb,
    unsigned short* __restrict__ nvtb)
{
    __shared__ unsigned short LDS[2][2][128 * 32];

    const unsigned short* A;
    const unsigned short* W;
    const float* bias;
    const float* dwm = nullptr;
    unsigned short* out;
    int epi;
    float scale = 1.f;
    switch (blockIdx.z) {
      // Q: fold log2(e) into the 1/sqrt(d) scale so attention works in exp2 domain
      case 0:  A = xq; W = wbf;           bias = ipb;        out = qb;   epi = 1; scale = 0.18033688011112042f; break;
      case 1:  A = xk; W = wbf + 1048576; bias = ipb + 1024; out = kb;   epi = 1; break;
      case 2:  A = xk; W = wbf + 2097152; bias = ipb + 2048; out = vtb;  epi = 2; break;
      case 3:  A = xn; W = wbf + 1048576; bias = ipb + 1024; out = nkb;  epi = 1; break;
      default: A = xn; W = wbf + 2097152; bias = ipb + 2048; out = nvtb; epi = 2; dwm = dwb; break;
    }

    const int tid = threadIdx.x;
    const int l = tid & 63, w = tid >> 6;
    const int brow = blockIdx.y * 128;
    const int bcol = blockIdx.x * 128;

    const int ch0 = w * 64 + l;
    const int ch1 = 256 + w * 64 + l;
    const unsigned short* gA0 = A + (size_t)(brow + (ch0 >> 2)) * E_ + (ch0 & 3) * 8;
    const unsigned short* gA1 = A + (size_t)(brow + (ch1 >> 2)) * E_ + (ch1 & 3) * 8;
    const unsigned short* gW0 = W + (size_t)(bcol + (ch0 >> 2)) * E_ + (ch0 & 3) * 8;
    const unsigned short* gW1 = W + (size_t)(bcol + (ch1 >> 2)) * E_ + (ch1 & 3) * 8;

    auto STAGE = [&](int buf, int kt) {
        gload16(gA0 + kt, &LDS[buf][0][(size_t)w * 512]);
        gload16(gA1 + kt, &LDS[buf][0][(size_t)(4 + w) * 512]);
        gload16(gW0 + kt, &LDS[buf][1][(size_t)w * 512]);
        gload16(gW1 + kt, &LDS[buf][1][(size_t)(4 + w) * 512]);
    };

    f32x4 acc[4][4];
    #pragma unroll
    for (int m = 0; m < 4; ++m)
        #pragma unroll
        for (int n = 0; n < 4; ++n)
            acc[m][n] = (f32x4){0.f, 0.f, 0.f, 0.f};

    const int wr = (w >> 1) * 64, wc = (w & 1) * 64;
    const int fr = l & 15, ko = (l >> 4) * 8;

    STAGE(0, 0);
    __syncthreads();
    for (int t = 0; t < 32; ++t) {
        const int cur = t & 1;
        if (t < 31) STAGE(cur ^ 1, (t + 1) * 32);
        short8 av[4], bv[4];
        #pragma unroll
        for (int m = 0; m < 4; ++m)
            av[m] = *reinterpret_cast<const short8*>(&LDS[cur][0][(wr + m * 16 + fr) * 32 + ko]);
        #pragma unroll
        for (int n = 0; n < 4; ++n)
            bv[n] = *reinterpret_cast<const short8*>(&LDS[cur][1][(wc + n * 16 + fr) * 32 + ko]);
        #pragma unroll
        for (int m = 0; m < 4; ++m)
            #pragma unroll
            for (int n = 0; n < 4; ++n)
                acc[m][n] = MFMA16(av[m], bv[n], acc[m][n]);
        if (t < 31) __syncthreads();
    }

    #pragma unroll
    for (int n = 0; n < 4; ++n) {
        const int c = bcol + wc + n * 16 + fr;
        const float bi = bias[c];
        #pragma unroll
        for (int m = 0; m < 4; ++m) {
            #pragma unroll
            for (int j = 0; j < 4; ++j) {
                const int r = brow + wr + m * 16 + (l >> 4) * 4 + j;
                float v = (acc[m][n][j] + bi) * scale;
                const int rn = r >> 2, b = r & 3, hh = c >> 6, dd = c & 63;
                if (epi == 1) {
                    out[((size_t)(b * H_ + hh) * 1024 + rn) * 64 + dd] = f2bf(v);
                } else {
                    if (dwm) v *= dwm[(size_t)r * H_ + hh];
                    out[(((size_t)(b * H_ + hh) * 32 + (rn >> 5)) * 64 + dd) * 32 + (rn & 31)] = f2bf(v);
                }
            }
        }
    }
}

// ---------------------------------------------------------------------------
// Output projection, hi/lo 3-term (unchanged from R3).
// ---------------------------------------------------------------------------
__global__ __launch_bounds__(256) void outproj_mfma(
    const unsigned short* __restrict__ ahi,
    const unsigned short* __restrict__ alo,
    const unsigned short* __restrict__ whi,
    const unsigned short* __restrict__ wlo,
    const float* __restrict__ out_b,
    float* __restrict__ out)
{
    __shared__ unsigned short LDS[2][4][128 * 32];

    const int tid = threadIdx.x;
    const int l = tid & 63, w = tid >> 6;
    const int brow = blockIdx.y * 128;
    const int bcol = blockIdx.x * 128;

    const int ch0 = w * 64 + l;
    const int ch1 = 256 + w * 64 + l;
    const size_t ra0 = (size_t)(brow + (ch0 >> 2)) * E_ + (ch0 & 3) * 8;
    const size_t ra1 = (size_t)(brow + (ch1 >> 2)) * E_ + (ch1 & 3) * 8;
    const size_t rb0 = (size_t)(bcol + (ch0 >> 2)) * E_ + (ch0 & 3) * 8;
    const size_t rb1 = (size_t)(bcol + (ch1 >> 2)) * E_ + (ch1 & 3) * 8;

    auto STAGE = [&](int buf, int kt) {
        gload16(ahi + ra0 + kt, &LDS[buf][0][(size_t)w * 512]);
        gload16(ahi + ra1 + kt, &LDS[buf][0][(size_t)(4 + w) * 512]);
        gload16(alo + ra0 + kt, &LDS[buf][1][(size_t)w * 512]);
        gload16(alo + ra1 + kt, &LDS[buf][1][(size_t)(4 + w) * 512]);
        gload16(whi + rb0 + kt, &LDS[buf][2][(size_t)w * 512]);
        gload16(whi + rb1 + kt, &LDS[buf][2][(size_t)(4 + w) * 512]);
        gload16(wlo + rb0 + kt, &LDS[buf][3][(size_t)w * 512]);
        gload16(wlo + rb1 + kt, &LDS[buf][3][(size_t)(4 + w) * 512]);
    };

    f32x4 acc[4][4];
    #pragma unroll
    for (int m = 0; m < 4; ++m)
        #pragma unroll
        for (int n = 0; n < 4; ++n)
            acc[m][n] = (f32x4){0.f, 0.f, 0.f, 0.f};

    const int wr = (w >> 1) * 64, wc = (w & 1) * 64;
    const int fr = l & 15, ko = (l >> 4) * 8;

    STAGE(0, 0);
    __syncthreads();
    for (int t = 0; t < 32; ++t) {
        const int cur = t & 1;
        if (t < 31) STAGE(cur ^ 1, (t + 1) * 32);
        short8 ah[4], al[4], bh[4], bl[4];
        #pragma unroll
        for (int m = 0; m < 4; ++m) {
            ah[m] = *reinterpret_cast<const short8*>(&LDS[cur][0][(wr + m * 16 + fr) * 32 + ko]);
            al[m] = *reinterpret_cast<const short8*>(&LDS[cur][1][(wr + m * 16 + fr) * 32 + ko]);
        }
        #pragma unroll
        for (int n = 0; n < 4; ++n) {
            bh[n] = *reinterpret_cast<const short8*>(&LDS[cur][2][(wc + n * 16 + fr) * 32 + ko]);
            bl[n] = *reinterpret_cast<const short8*>(&LDS[cur][3][(wc + n * 16 + fr) * 32 + ko]);
        }
        #pragma unroll
        for (int m = 0; m < 4; ++m)
            #pragma unroll
            for (int n = 0; n < 4; ++n) {
                acc[m][n] = MFMA16(ah[m], bh[n], acc[m][n]);
                acc[m][n] = MFMA16(al[m], bh[n], acc[m][n]);
                acc[m][n] = MFMA16(ah[m], bl[n], acc[m][n]);
            }
        if (t < 31) __syncthreads();
    }

    #pragma unroll
    for (int n = 0; n < 4; ++n) {
        const int c = bcol + wc + n * 16 + fr;
        const float bi = out_b[c];
        #pragma unroll
        for (int m = 0; m < 4; ++m)
            #pragma unroll
            for (int j = 0; j < 4; ++j) {
                const int r = brow + wr + m * 16 + (l >> 4) * 4 + j;
                out[(size_t)r * E_ + c] = acc[m][n][j] + bi;
            }
    }
}

// ---------------------------------------------------------------------------
// MFMA flash attention, SPLIT-S: blockIdx.z = half (0: leaf 1024, 1: node
// 1023+pad). Grid (64, 16, 2) = 2048 blocks -> 8 blocks/CU, 100% occupancy.
// exp2 domain (log2e folded into Q scale); mask sentinel -60000 / mold init
// -30000 makes masked P underflow to exact 0 (no cndmask); defer-max skips
// rescale unless tile max exceeds running max + 8.
// Partial (acc f32, m, l) per row -> merged by merge_kernel.
// ---------------------------------------------------------------------------
__global__ __launch_bounds__(256, 8) void attn_mfma(
    const unsigned short* __restrict__ qbf,
    const unsigned short* __restrict__ kbf,
    const unsigned short* __restrict__ nkbf,
    const unsigned short* __restrict__ vtb,
    const unsigned short* __restrict__ nvtb,
    const unsigned char* __restrict__ kpm,
    const unsigned char* __restrict__ npm,
    float* __restrict__ pacc,
    float* __restrict__ pm,
    float* __restrict__ pl)
{
    __shared__ float maskS[1024];
    __shared__ int tmask[16];
    __shared__ unsigned short Pl[4][16 * 64];   // per-wave, XOR-swizzled rows

    const int tid = threadIdx.x;
    const int l = tid & 63, w = tid >> 6;
    const int bh = blockIdx.x, b = bh >> 4;
    const int t0 = blockIdx.y * 64;
    const int half = blockIdx.z;

    if (tid < 16) tmask[tid] = 0;
    __syncthreads();
    for (int s = tid; s < 1024; s += 256) {
        float mv;
        if (half == 0) mv = kpm[(size_t)b * N_ + s] ? -60000.f : 0.f;
        else           mv = (s < M_ && !npm[(size_t)b * M_ + s]) ? 0.f : -60000.f;
        maskS[s] = mv;
        if (mv != 0.f) atomicOr(&tmask[s >> 6], 1);
    }
    __syncthreads();

    const unsigned short* kb_ = half ? nkbf : kbf;
    const unsigned short* vb_ = half ? nvtb : vtb;

    const int qrow = t0 + w * 16 + (l & 15);
    const short8 aq0 = *reinterpret_cast<const short8*>(&qbf[((size_t)bh * T_ + qrow) * 64 + (l >> 4) * 8]);
    const short8 aq1 = *reinterpret_cast<const short8*>(&qbf[((size_t)bh * T_ + qrow) * 64 + 32 + (l >> 4) * 8]);

    float mold[4], lr[4];
    #pragma unroll
    for (int j = 0; j < 4; ++j) { mold[j] = -30000.f; lr[j] = 0.f; }
    f32x4 acco[4];
    #pragma unroll
    for (int n = 0; n < 4; ++n) acco[n] = (f32x4){0.f, 0.f, 0.f, 0.f};

    unsigned short* const Pw = &Pl[w][0];
    const int prow_r = l & 15;
    const int rofs0 = ((prow_r * 128 + (l >> 4) * 16) ^ ((prow_r & 7) << 4)) >> 1;
    const int rofs1 = ((prow_r * 128 + 64 + (l >> 4) * 16) ^ ((prow_r & 7) << 4)) >> 1;

    for (int s0 = 0; s0 < 1024; s0 += 64) {
        // ---- QK^T ----
        f32x4 accs[4];
        #pragma unroll
        for (int n = 0; n < 4; ++n) accs[n] = (f32x4){0.f, 0.f, 0.f, 0.f};
        __builtin_amdgcn_s_setprio(1);
        #pragma unroll
        for (int n = 0; n < 4; ++n) {
            const size_t krow = ((size_t)bh * 1024 + s0 + n * 16 + (l & 15)) * 64;
            const short8 k0 = *reinterpret_cast<const short8*>(&kb_[krow + (l >> 4) * 8]);
            const short8 k1 = *reinterpret_cast<const short8*>(&kb_[krow + 32 + (l >> 4) * 8]);
            accs[n] = MFMA16(aq0, k0, accs[n]);
            accs[n] = MFMA16(aq1, k1, accs[n]);
        }
        __builtin_amdgcn_s_setprio(0);

        // ---- mask (only if tile has any masked col) ----
        float sv[4][4];
        #pragma unroll
        for (int n = 0; n < 4; ++n)
            #pragma unroll
            for (int j = 0; j < 4; ++j)
                sv[n][j] = accs[n][j];
        if (tmask[s0 >> 6]) {
            #pragma unroll
            for (int n = 0; n < 4; ++n) {
                const float mz = maskS[s0 + n * 16 + (l & 15)];
                #pragma unroll
                for (int j = 0; j < 4; ++j) sv[n][j] += mz;
            }
        }

        // ---- row max (in-lane over n, then 16-lane col group) ----
        float mx[4] = {-60000.f, -60000.f, -60000.f, -60000.f};
        #pragma unroll
        for (int n = 0; n < 4; ++n)
            #pragma unroll
            for (int j = 0; j < 4; ++j) mx[j] = fmaxf(mx[j], sv[n][j]);
        #pragma unroll
        for (int j = 0; j < 4; ++j) {
            mx[j] = fmaxf(mx[j], __shfl_xor(mx[j], 1));
            mx[j] = fmaxf(mx[j], __shfl_xor(mx[j], 2));
            mx[j] = fmaxf(mx[j], __shfl_xor(mx[j], 4));
            mx[j] = fmaxf(mx[j], __shfl_xor(mx[j], 8));
        }

        // ---- defer-max: rescale only when max grew past threshold ----
        int need = 0;
        #pragma unroll
        for (int j = 0; j < 4; ++j) need |= (mx[j] > mold[j] + 8.f);
        if (__any(need)) {
            #pragma unroll
            for (int j = 0; j < 4; ++j) {
                const float mn = fmaxf(mold[j], mx[j]);
                const float f = __builtin_amdgcn_exp2f(mold[j] - mn);
                mold[j] = mn;
                lr[j] *= f;
                #pragma unroll
                for (int n = 0; n < 4; ++n) acco[n][j] *= f;
            }
        }

        // ---- P = exp2(sv - m); masked entries underflow to 0 ----
        float ps[4] = {0.f, 0.f, 0.f, 0.f};
        unsigned short pb[4][4];
        #pragma unroll
        for (int n = 0; n < 4; ++n)
            #pragma unroll
            for (int j = 0; j < 4; ++j) {
                const float p = __builtin_amdgcn_exp2f(sv[n][j] - mold[j]);
                pb[n][j] = f2bf(p);
                ps[j] += p;
            }
        #pragma unroll
        for (int j = 0; j < 4; ++j) {
            float p = ps[j];
            p += __shfl_xor(p, 1);
            p += __shfl_xor(p, 2);
            p += __shfl_xor(p, 4);
            p += __shfl_xor(p, 8);
            lr[j] += p;
        }

        // ---- P -> LDS (swizzled) -> A-frags ----
        #pragma unroll
        for (int j = 0; j < 4; ++j) {
            const int prow = (l >> 4) * 4 + j;
            const int rb = prow * 128;
            const int sw = (prow & 7) << 4;
            #pragma unroll
            for (int n = 0; n < 4; ++n) {
                const int byte = (rb + (n * 16 + (l & 15)) * 2) ^ sw;
                Pw[byte >> 1] = pb[n][j];
            }
        }
        const short8 ap0 = *reinterpret_cast<const short8*>(Pw + rofs0);
        const short8 ap1 = *reinterpret_cast<const short8*>(Pw + rofs1);

        // ---- PV ----
        const int kp = s0 >> 5;
        __builtin_amdgcn_s_setprio(1);
        #pragma unroll
        for (int n = 0; n < 4; ++n) {
            const size_t vr0 = (((size_t)bh * 32 + kp)     * 64 + n * 16 + (l & 15)) * 32;
            const size_t vr1 = (((size_t)bh * 32 + kp + 1) * 64 + n * 16 + (l & 15)) * 32;
            const short8 v0 = *reinterpret_cast<const short8*>(&vb_[vr0 + (l >> 4) * 8]);
            const short8 v1 = *reinterpret_cast<const short8*>(&vb_[vr1 + (l >> 4) * 8]);
            acco[n] = MFMA16(ap0, v0, acco[n]);
            acco[n] = MFMA16(ap1, v1, acco[n]);
        }
        __builtin_amdgcn_s_setprio(0);
    }

    // ---- epilogue: raw partial acc + (m, l) per row ----
    const size_t rowbase = ((size_t)(half * 64 + bh)) * 1024 + t0 + w * 16;
    #pragma unroll
    for (int j = 0; j < 4; ++j) {
        const int rr = (l >> 4) * 4 + j;
        #pragma unroll
        for (int n = 0; n < 4; ++n)
            pacc[(rowbase + rr) * 64 + n * 16 + (l & 15)] = acco[n][j];
        if ((l & 15) == 0) {
            pm[rowbase + rr] = mold[j];
            pl[rowbase + rr] = lr[j];
        }
    }
}

// ---------------------------------------------------------------------------
// Merge the two S-halves: o = (a0*w0 + a1*w1) / (l0*w0 + l1*w1), w = 2^(m-m*).
// Writes hi/lo bf16 in (t,b,e) layout for the output projection.
// ---------------------------------------------------------------------------
__global__ void merge_kernel(const float* __restrict__ pacc,
                             const float* __restrict__ pm,
                             const float* __restrict__ pl,
                             unsigned short* __restrict__ ohi,
                             unsigned short* __restrict__ olo)
{
    const int g = blockIdx.x * 256 + threadIdx.x;
    const int row = g >> 4;              // bh*1024 + t
    const int d4 = (g & 15) * 4;
    const int bh = row >> 10, t = row & 1023;
    const int b = bh >> 4, h = bh & 15;

    const float m0 = pm[row], m1 = pm[65536 + row];
    const float l0 = pl[row], l1 = pl[65536 + row];
    const float ms = fmaxf(m0, m1);
    const float w0 = __builtin_amdgcn_exp2f(m0 - ms);
    const float w1 = __builtin_amdgcn_exp2f(m1 - ms);
    const float den = 1.f / (l0 * w0 + l1 * w1);

    const float4 a0 = *reinterpret_cast<const float4*>(&pacc[(size_t)row * 64 + d4]);
    const float4 a1 = *reinterpret_cast<const float4*>(&pacc[(size_t)(65536 + row) * 64 + d4]);

    float o[4] = {
        (a0.x * w0 + a1.x * w1) * den,
        (a0.y * w0 + a1.y * w1) * den,
        (a0.z * w0 + a1.z * w1) * den,
        (a0.w * w0 + a1.w * w1) * den,
    };
    ushort4 vh_, vl_;
    unsigned short hh[4], ll[4];
    #pragma unroll
    for (int k = 0; k < 4; ++k) {
        hh[k] = f2bf(o[k]);
        ll[k] = f2bf(o[k] - bf2f(hh[k]));
    }
    vh_.x = hh[0]; vh_.y = hh[1]; vh_.z = hh[2]; vh_.w = hh[3];
    vl_.x = ll[0]; vl_.y = ll[1]; vl_.z = ll[2]; vl_.w = ll[3];
    const size_t oidx = ((size_t)t * B_ + b) * E_ + h * D_ + d4;
    *reinterpret_cast<ushort4*>(&ohi[oidx]) = vh_;
    *reinterpret_cast<ushort4*>(&olo[oidx]) = vl_;
}

// ---------------------------------------------------------------------------
extern "C" void kernel_launch(void* const* d_in, const int* in_sizes, int n_in,
                              void* d_out, int out_size, void* d_ws, size_t ws_size,
                              hipStream_t stream) {
    const float* query    = (const float*)d_in[0];
    const float* key      = (const float*)d_in[1];
    const float* node_key = (const float*)d_in[2];
    const float* ipw      = (const float*)d_in[3];
    const float* ipb      = (const float*)d_in[4];
    const float* out_w    = (const float*)d_in[5];
    const float* out_b    = (const float*)d_in[6];
    const float* dw_w     = (const float*)d_in[7];
    const float* dw_b     = (const float*)d_in[8];
    const unsigned char* kpm = (const unsigned char*)d_in[9];
    const unsigned char* npm = (const unsigned char*)d_in[10];
    float* out = (float*)d_out;

    char* p = (char*)d_ws;
    auto alloc = [&](size_t bytes) {
        char* r = p;
        p += (bytes + 255) & ~(size_t)255;
        return r;
    };
    // xq..pad region (32 MiB) is reused as pacc after proj_mfma has consumed it
    unsigned short* xq    = (unsigned short*)alloc((size_t)4096 * 1024 * 2);
    unsigned short* xk    = (unsigned short*)alloc((size_t)4096 * 1024 * 2);
    unsigned short* xn    = (unsigned short*)alloc((size_t)4096 * 1024 * 2);
    unsigned short* wbf   = (unsigned short*)alloc((size_t)3072 * 1024 * 2);
    (void)alloc((size_t)2 * 1024 * 1024);   // pad so pacc (32 MiB) fits over xq..here
    unsigned short* wohi  = (unsigned short*)alloc((size_t)1024 * 1024 * 2);
    unsigned short* wolo  = (unsigned short*)alloc((size_t)1024 * 1024 * 2);
    unsigned short* qb    = (unsigned short*)alloc((size_t)64 * 1024 * 64 * 2);
    unsigned short* kb_   = (unsigned short*)alloc((size_t)64 * 1024 * 64 * 2);
    unsigned short* nkb   = (unsigned short*)alloc((size_t)64 * 1024 * 64 * 2);
    unsigned short* vtb   = (unsigned short*)alloc((size_t)64 * 1024 * 64 * 2);
    unsigned short* nvtb  = (unsigned short*)alloc((size_t)64 * 1024 * 64 * 2);
    unsigned short* ohi   = (unsigned short*)alloc((size_t)4096 * 1024 * 2);
    unsigned short* olo   = (unsigned short*)alloc((size_t)4096 * 1024 * 2);
    float*          dwb   = (float*)alloc((size_t)4096 * 16 * 4);
    float*          pm    = (float*)alloc((size_t)2 * 65536 * 4);
    float*          pl    = (float*)alloc((size_t)2 * 65536 * 4);
    float*          pacc  = (float*)xq;     // 2*64*1024*64 f32 = 32 MiB overlay

    const dim3 blk(256);

    // 1) conversions
    f2bf_kernel<<<dim3(4096), blk, 0, stream>>>(query,    xq, 4194304, 4194304);
    f2bf_kernel<<<dim3(4096), blk, 0, stream>>>(key,      xk, 4194304, 4194304);
    f2bf_kernel<<<dim3(4096), blk, 0, stream>>>(node_key, xn, 4190208, 4194304);
    f2bf_kernel<<<dim3(3072), blk, 0, stream>>>(ipw,      wbf, 3145728, 3145728);
    f2bf_hilo_kernel<<<dim3(1024), blk, 0, stream>>>(out_w, wohi, wolo, 1048576);

    // 2) dw gate
    dw_kernel<<<dim3(M_ * B_), blk, 0, stream>>>(node_key, dw_w, dw_b, dwb);

    // 3) fused input projections
    proj_mfma<<<dim3(8, 32, 5), blk, 0, stream>>>(xq, xk, xn, wbf, ipb, dwb,
                                                  qb, kb_, vtb, nkb, nvtb);

    // 4) attention, split-S (overwrites xq-region with pacc)
    attn_mfma<<<dim3(64, 16, 2), blk, 0, stream>>>(qb, kb_, nkb, vtb, nvtb,
                                                   kpm, npm, pacc, pm, pl);

    // 5) merge halves -> hi/lo bf16 o
    merge_kernel<<<dim3(4096), blk, 0, stream>>>(pacc, pm, pl, ohi, olo);

    // 6) output projection (hi/lo 3-term) -> d_out fp32
    outproj_mfma<<<dim3(8, 32), blk, 0, stream>>>(ohi, olo, wohi, wolo, out_b, out);
}

// Round 5
// 370.204 us; speedup vs baseline: 1.2283x; 1.2283x over previous
//
#include <hip/hip_runtime.h>
#include <cstdint>
#include <cstddef>

using short8 = __attribute__((ext_vector_type(8))) short;
using f32x4  = __attribute__((ext_vector_type(4))) float;

constexpr int T_ = 1024;
constexpr int N_ = 1024;
constexpr int M_ = 1023;
constexpr int B_ = 4;
constexpr int E_ = 1024;
constexpr int H_ = 16;
constexpr int D_ = 64;

#define MFMA16(a, b, c) __builtin_amdgcn_mfma_f32_16x16x32_bf16((a), (b), (c), 0, 0, 0)

__device__ __forceinline__ unsigned short f2bf(float f) {
    unsigned int u = __float_as_uint(f);
    u += 0x7FFF + ((u >> 16) & 1);          // round-to-nearest-even
    return (unsigned short)(u >> 16);
}
__device__ __forceinline__ float bf2f(unsigned short s) {
    return __uint_as_float(((unsigned int)s) << 16);
}

// global -> LDS direct copy, 16 B per lane. LDS dest must be wave-uniform;
// HW writes lds_base + lane*16.
typedef __attribute__((address_space(1))) const unsigned char gc_byte;
typedef __attribute__((address_space(3))) unsigned char lds_byte;
__device__ __forceinline__ void gload16(const void* g, void* lds) {
    __builtin_amdgcn_global_load_lds((gc_byte*)(uintptr_t)g,
                                     (lds_byte*)(unsigned int)(uintptr_t)lds,
                                     16, 0, 0);
}

// ---------------------------------------------------------------------------
// fp32 -> bf16 conversion, with zero-padding from n..npad (npad % 4 == 0)
// ---------------------------------------------------------------------------
__global__ void f2bf_kernel(const float* __restrict__ src,
                            unsigned short* __restrict__ dst, int n, int npad)
{
    int i = (blockIdx.x * 256 + threadIdx.x) * 4;
    if (i >= npad) return;
    if (i + 4 <= n) {
        const float4 v = *reinterpret_cast<const float4*>(src + i);
        ushort4 o;
        o.x = f2bf(v.x); o.y = f2bf(v.y); o.z = f2bf(v.z); o.w = f2bf(v.w);
        *reinterpret_cast<ushort4*>(dst + i) = o;
    } else {
        for (int k = 0; k < 4; ++k)
            dst[i + k] = (i + k < n) ? f2bf(src[i + k]) : (unsigned short)0;
    }
}

// fp32 -> (bf16 hi, bf16 lo) split.  n % 4 == 0
__global__ void f2bf_hilo_kernel(const float* __restrict__ src,
                                 unsigned short* __restrict__ dhi,
                                 unsigned short* __restrict__ dlo, int n)
{
    int i = (blockIdx.x * 256 + threadIdx.x) * 4;
    if (i >= n) return;
    const float4 v = *reinterpret_cast<const float4*>(src + i);
    float a[4] = {v.x, v.y, v.z, v.w};
    ushort4 hi, lo;
    unsigned short h[4], l[4];
    #pragma unroll
    for (int k = 0; k < 4; ++k) {
        h[k] = f2bf(a[k]);
        l[k] = f2bf(a[k] - bf2f(h[k]));
    }
    hi.x = h[0]; hi.y = h[1]; hi.z = h[2]; hi.w = h[3];
    lo.x = l[0]; lo.y = l[1]; lo.z = l[2]; lo.w = l[3];
    *reinterpret_cast<ushort4*>(dhi + i) = hi;
    *reinterpret_cast<ushort4*>(dlo + i) = lo;
}

// ---------------------------------------------------------------------------
// dw gate kernel (fp32): dw[r*H+h] = sigmoid(node_key_r . dw_w[h] + dw_b[h])
// ---------------------------------------------------------------------------
__global__ void dw_kernel(const float* __restrict__ node_key,
                          const float* __restrict__ dw_w,
                          const float* __restrict__ dw_b,
                          float* __restrict__ dwb)
{
    __shared__ float rowbuf[E_];
    const int r = blockIdx.x;
    const int tid = threadIdx.x;
    for (int idx = tid; idx < E_; idx += 256)
        rowbuf[idx] = node_key[(size_t)r * E_ + idx];
    __syncthreads();
    const int h = tid >> 4;
    const int lane = tid & 15;
    float acc = 0.f;
    const float* wrow = dw_w + (size_t)h * E_;
    for (int k = lane; k < E_; k += 16)
        acc = fmaf(rowbuf[k], wrow[k], acc);
    acc += __shfl_xor(acc, 8);
    acc += __shfl_xor(acc, 4);
    acc += __shfl_xor(acc, 2);
    acc += __shfl_xor(acc, 1);
    if (lane == 0) {
        float x = acc + dw_b[h];
        dwb[(size_t)r * H_ + h] = 1.f / (1.f + __expf(-x));
    }
}

// ---------------------------------------------------------------------------
// Fused input projections (unchanged from R3; Q-scale folds log2e for exp2).
// ---------------------------------------------------------------------------
__global__ __launch_bounds__(256) void proj_mfma(
    const unsigned short* __restrict__ xq,
    const unsigned short* __restrict__ xk,
    const unsigned short* __restrict__ xn,
    const unsigned short* __restrict__ wbf,
    const float* __restrict__ ipb,
    const float* __restrict__ dwb,
    unsigned short* __restrict__ qb,
    unsigned short* __restrict__ kb,
    unsigned short* __restrict__ vtb,
    unsigned short* __restrict__ nkb,
    unsigned short* __restrict__ nvtb)
{
    __shared__ unsigned short LDS[2][2][128 * 32];

    const unsigned short* A;
    const unsigned short* W;
    const float* bias;
    const float* dwm = nullptr;
    unsigned short* out;
    int epi;
    float scale = 1.f;
    switch (blockIdx.z) {
      case 0:  A = xq; W = wbf;           bias = ipb;        out = qb;   epi = 1; scale = 0.18033688011112042f; break;
      case 1:  A = xk; W = wbf + 1048576; bias = ipb + 1024; out = kb;   epi = 1; break;
      case 2:  A = xk; W = wbf + 2097152; bias = ipb + 2048; out = vtb;  epi = 2; break;
      case 3:  A = xn; W = wbf + 1048576; bias = ipb + 1024; out = nkb;  epi = 1; break;
      default: A = xn; W = wbf + 2097152; bias = ipb + 2048; out = nvtb; epi = 2; dwm = dwb; break;
    }

    const int tid = threadIdx.x;
    const int l = tid & 63, w = tid >> 6;
    const int brow = blockIdx.y * 128;
    const int bcol = blockIdx.x * 128;

    const int ch0 = w * 64 + l;
    const int ch1 = 256 + w * 64 + l;
    const unsigned short* gA0 = A + (size_t)(brow + (ch0 >> 2)) * E_ + (ch0 & 3) * 8;
    const unsigned short* gA1 = A + (size_t)(brow + (ch1 >> 2)) * E_ + (ch1 & 3) * 8;
    const unsigned short* gW0 = W + (size_t)(bcol + (ch0 >> 2)) * E_ + (ch0 & 3) * 8;
    const unsigned short* gW1 = W + (size_t)(bcol + (ch1 >> 2)) * E_ + (ch1 & 3) * 8;

    auto STAGE = [&](int buf, int kt) {
        gload16(gA0 + kt, &LDS[buf][0][(size_t)w * 512]);
        gload16(gA1 + kt, &LDS[buf][0][(size_t)(4 + w) * 512]);
        gload16(gW0 + kt, &LDS[buf][1][(size_t)w * 512]);
        gload16(gW1 + kt, &LDS[buf][1][(size_t)(4 + w) * 512]);
    };

    f32x4 acc[4][4];
    #pragma unroll
    for (int m = 0; m < 4; ++m)
        #pragma unroll
        for (int n = 0; n < 4; ++n)
            acc[m][n] = (f32x4){0.f, 0.f, 0.f, 0.f};

    const int wr = (w >> 1) * 64, wc = (w & 1) * 64;
    const int fr = l & 15, ko = (l >> 4) * 8;

    STAGE(0, 0);
    __syncthreads();
    for (int t = 0; t < 32; ++t) {
        const int cur = t & 1;
        if (t < 31) STAGE(cur ^ 1, (t + 1) * 32);
        short8 av[4], bv[4];
        #pragma unroll
        for (int m = 0; m < 4; ++m)
            av[m] = *reinterpret_cast<const short8*>(&LDS[cur][0][(wr + m * 16 + fr) * 32 + ko]);
        #pragma unroll
        for (int n = 0; n < 4; ++n)
            bv[n] = *reinterpret_cast<const short8*>(&LDS[cur][1][(wc + n * 16 + fr) * 32 + ko]);
        #pragma unroll
        for (int m = 0; m < 4; ++m)
            #pragma unroll
            for (int n = 0; n < 4; ++n)
                acc[m][n] = MFMA16(av[m], bv[n], acc[m][n]);
        if (t < 31) __syncthreads();
    }

    #pragma unroll
    for (int n = 0; n < 4; ++n) {
        const int c = bcol + wc + n * 16 + fr;
        const float bi = bias[c];
        #pragma unroll
        for (int m = 0; m < 4; ++m) {
            #pragma unroll
            for (int j = 0; j < 4; ++j) {
                const int r = brow + wr + m * 16 + (l >> 4) * 4 + j;
                float v = (acc[m][n][j] + bi) * scale;
                const int rn = r >> 2, b = r & 3, hh = c >> 6, dd = c & 63;
                if (epi == 1) {
                    out[((size_t)(b * H_ + hh) * 1024 + rn) * 64 + dd] = f2bf(v);
                } else {
                    if (dwm) v *= dwm[(size_t)r * H_ + hh];
                    out[(((size_t)(b * H_ + hh) * 32 + (rn >> 5)) * 64 + dd) * 32 + (rn & 31)] = f2bf(v);
                }
            }
        }
    }
}

// ---------------------------------------------------------------------------
// Output projection, hi/lo 3-term (unchanged from R3).
// ---------------------------------------------------------------------------
__global__ __launch_bounds__(256) void outproj_mfma(
    const unsigned short* __restrict__ ahi,
    const unsigned short* __restrict__ alo,
    const unsigned short* __restrict__ whi,
    const unsigned short* __restrict__ wlo,
    const float* __restrict__ out_b,
    float* __restrict__ out)
{
    __shared__ unsigned short LDS[2][4][128 * 32];

    const int tid = threadIdx.x;
    const int l = tid & 63, w = tid >> 6;
    const int brow = blockIdx.y * 128;
    const int bcol = blockIdx.x * 128;

    const int ch0 = w * 64 + l;
    const int ch1 = 256 + w * 64 + l;
    const size_t ra0 = (size_t)(brow + (ch0 >> 2)) * E_ + (ch0 & 3) * 8;
    const size_t ra1 = (size_t)(brow + (ch1 >> 2)) * E_ + (ch1 & 3) * 8;
    const size_t rb0 = (size_t)(bcol + (ch0 >> 2)) * E_ + (ch0 & 3) * 8;
    const size_t rb1 = (size_t)(bcol + (ch1 >> 2)) * E_ + (ch1 & 3) * 8;

    auto STAGE = [&](int buf, int kt) {
        gload16(ahi + ra0 + kt, &LDS[buf][0][(size_t)w * 512]);
        gload16(ahi + ra1 + kt, &LDS[buf][0][(size_t)(4 + w) * 512]);
        gload16(alo + ra0 + kt, &LDS[buf][1][(size_t)w * 512]);
        gload16(alo + ra1 + kt, &LDS[buf][1][(size_t)(4 + w) * 512]);
        gload16(whi + rb0 + kt, &LDS[buf][2][(size_t)w * 512]);
        gload16(whi + rb1 + kt, &LDS[buf][2][(size_t)(4 + w) * 512]);
        gload16(wlo + rb0 + kt, &LDS[buf][3][(size_t)w * 512]);
        gload16(wlo + rb1 + kt, &LDS[buf][3][(size_t)(4 + w) * 512]);
    };

    f32x4 acc[4][4];
    #pragma unroll
    for (int m = 0; m < 4; ++m)
        #pragma unroll
        for (int n = 0; n < 4; ++n)
            acc[m][n] = (f32x4){0.f, 0.f, 0.f, 0.f};

    const int wr = (w >> 1) * 64, wc = (w & 1) * 64;
    const int fr = l & 15, ko = (l >> 4) * 8;

    STAGE(0, 0);
    __syncthreads();
    for (int t = 0; t < 32; ++t) {
        const int cur = t & 1;
        if (t < 31) STAGE(cur ^ 1, (t + 1) * 32);
        short8 ah[4], al[4], bh[4], bl[4];
        #pragma unroll
        for (int m = 0; m < 4; ++m) {
            ah[m] = *reinterpret_cast<const short8*>(&LDS[cur][0][(wr + m * 16 + fr) * 32 + ko]);
            al[m] = *reinterpret_cast<const short8*>(&LDS[cur][1][(wr + m * 16 + fr) * 32 + ko]);
        }
        #pragma unroll
        for (int n = 0; n < 4; ++n) {
            bh[n] = *reinterpret_cast<const short8*>(&LDS[cur][2][(wc + n * 16 + fr) * 32 + ko]);
            bl[n] = *reinterpret_cast<const short8*>(&LDS[cur][3][(wc + n * 16 + fr) * 32 + ko]);
        }
        #pragma unroll
        for (int m = 0; m < 4; ++m)
            #pragma unroll
            for (int n = 0; n < 4; ++n) {
                acc[m][n] = MFMA16(ah[m], bh[n], acc[m][n]);
                acc[m][n] = MFMA16(al[m], bh[n], acc[m][n]);
                acc[m][n] = MFMA16(ah[m], bl[n], acc[m][n]);
            }
        if (t < 31) __syncthreads();
    }

    #pragma unroll
    for (int n = 0; n < 4; ++n) {
        const int c = bcol + wc + n * 16 + fr;
        const float bi = out_b[c];
        #pragma unroll
        for (int m = 0; m < 4; ++m)
            #pragma unroll
            for (int j = 0; j < 4; ++j) {
                const int r = brow + wr + m * 16 + (l >> 4) * 4 + j;
                out[(size_t)r * E_ + c] = acc[m][n][j] + bi;
            }
    }
}

// ---------------------------------------------------------------------------
// MFMA flash attention, SPLIT-S (R4 structure, register-pressure fixed):
// NO min-waves launch bound (R4's (256,8) capped unified VGPR+AGPR at 64 ->
// accumulator spill to scratch, 566 MB FETCH). Mask applied in-place to the
// QK accumulator (no separate sv[4][4]) to keep regs near 60.
// ---------------------------------------------------------------------------
__global__ __launch_bounds__(256) void attn_mfma(
    const unsigned short* __restrict__ qbf,
    const unsigned short* __restrict__ kbf,
    const unsigned short* __restrict__ nkbf,
    const unsigned short* __restrict__ vtb,
    const unsigned short* __restrict__ nvtb,
    const unsigned char* __restrict__ kpm,
    const unsigned char* __restrict__ npm,
    float* __restrict__ pacc,
    float* __restrict__ pm,
    float* __restrict__ pl)
{
    __shared__ float maskS[1024];
    __shared__ int tmask[16];
    __shared__ unsigned short Pl[4][16 * 64];   // per-wave, XOR-swizzled rows

    const int tid = threadIdx.x;
    const int l = tid & 63, w = tid >> 6;
    const int bh = blockIdx.x, b = bh >> 4;
    const int t0 = blockIdx.y * 64;
    const int half = blockIdx.z;

    if (tid < 16) tmask[tid] = 0;
    __syncthreads();
    for (int s = tid; s < 1024; s += 256) {
        float mv;
        if (half == 0) mv = kpm[(size_t)b * N_ + s] ? -60000.f : 0.f;
        else           mv = (s < M_ && !npm[(size_t)b * M_ + s]) ? 0.f : -60000.f;
        maskS[s] = mv;
        if (mv != 0.f) atomicOr(&tmask[s >> 6], 1);
    }
    __syncthreads();

    const unsigned short* kb_ = half ? nkbf : kbf;
    const unsigned short* vb_ = half ? nvtb : vtb;

    const int qrow = t0 + w * 16 + (l & 15);
    const short8 aq0 = *reinterpret_cast<const short8*>(&qbf[((size_t)bh * T_ + qrow) * 64 + (l >> 4) * 8]);
    const short8 aq1 = *reinterpret_cast<const short8*>(&qbf[((size_t)bh * T_ + qrow) * 64 + 32 + (l >> 4) * 8]);

    float mold[4], lr[4];
    #pragma unroll
    for (int j = 0; j < 4; ++j) { mold[j] = -30000.f; lr[j] = 0.f; }
    f32x4 acco[4];
    #pragma unroll
    for (int n = 0; n < 4; ++n) acco[n] = (f32x4){0.f, 0.f, 0.f, 0.f};

    unsigned short* const Pw = &Pl[w][0];
    const int prow_r = l & 15;
    const int rofs0 = ((prow_r * 128 + (l >> 4) * 16) ^ ((prow_r & 7) << 4)) >> 1;
    const int rofs1 = ((prow_r * 128 + 64 + (l >> 4) * 16) ^ ((prow_r & 7) << 4)) >> 1;

    for (int s0 = 0; s0 < 1024; s0 += 64) {
        // ---- QK^T ----
        f32x4 accs[4];
        #pragma unroll
        for (int n = 0; n < 4; ++n) accs[n] = (f32x4){0.f, 0.f, 0.f, 0.f};
        __builtin_amdgcn_s_setprio(1);
        #pragma unroll
        for (int n = 0; n < 4; ++n) {
            const size_t krow = ((size_t)bh * 1024 + s0 + n * 16 + (l & 15)) * 64;
            const short8 k0 = *reinterpret_cast<const short8*>(&kb_[krow + (l >> 4) * 8]);
            const short8 k1 = *reinterpret_cast<const short8*>(&kb_[krow + 32 + (l >> 4) * 8]);
            accs[n] = MFMA16(aq0, k0, accs[n]);
            accs[n] = MFMA16(aq1, k1, accs[n]);
        }
        __builtin_amdgcn_s_setprio(0);

        // ---- mask in-place (only if tile has any masked col) ----
        if (tmask[s0 >> 6]) {
            #pragma unroll
            for (int n = 0; n < 4; ++n) {
                const float mz = maskS[s0 + n * 16 + (l & 15)];
                #pragma unroll
                for (int j = 0; j < 4; ++j) accs[n][j] += mz;
            }
        }

        // ---- row max ----
        float mx[4] = {-60000.f, -60000.f, -60000.f, -60000.f};
        #pragma unroll
        for (int n = 0; n < 4; ++n)
            #pragma unroll
            for (int j = 0; j < 4; ++j) mx[j] = fmaxf(mx[j], accs[n][j]);
        #pragma unroll
        for (int j = 0; j < 4; ++j) {
            mx[j] = fmaxf(mx[j], __shfl_xor(mx[j], 1));
            mx[j] = fmaxf(mx[j], __shfl_xor(mx[j], 2));
            mx[j] = fmaxf(mx[j], __shfl_xor(mx[j], 4));
            mx[j] = fmaxf(mx[j], __shfl_xor(mx[j], 8));
        }

        // ---- defer-max: rescale only when max grew past threshold ----
        int need = 0;
        #pragma unroll
        for (int j = 0; j < 4; ++j) need |= (mx[j] > mold[j] + 8.f);
        if (__any(need)) {
            #pragma unroll
            for (int j = 0; j < 4; ++j) {
                const float mn = fmaxf(mold[j], mx[j]);
                const float f = __builtin_amdgcn_exp2f(mold[j] - mn);
                mold[j] = mn;
                lr[j] *= f;
                #pragma unroll
                for (int n = 0; n < 4; ++n) acco[n][j] *= f;
            }
        }

        // ---- P = exp2(s - m); masked entries underflow to exact 0 ----
        float ps[4] = {0.f, 0.f, 0.f, 0.f};
        unsigned short pb[4][4];
        #pragma unroll
        for (int n = 0; n < 4; ++n)
            #pragma unroll
            for (int j = 0; j < 4; ++j) {
                const float p = __builtin_amdgcn_exp2f(accs[n][j] - mold[j]);
                pb[n][j] = f2bf(p);
                ps[j] += p;
            }
        #pragma unroll
        for (int j = 0; j < 4; ++j) {
            float p = ps[j];
            p += __shfl_xor(p, 1);
            p += __shfl_xor(p, 2);
            p += __shfl_xor(p, 4);
            p += __shfl_xor(p, 8);
            lr[j] += p;
        }

        // ---- P -> LDS (swizzled) -> A-frags ----
        #pragma unroll
        for (int j = 0; j < 4; ++j) {
            const int prow = (l >> 4) * 4 + j;
            const int rb = prow * 128;
            const int sw = (prow & 7) << 4;
            #pragma unroll
            for (int n = 0; n < 4; ++n) {
                const int byte = (rb + (n * 16 + (l & 15)) * 2) ^ sw;
                Pw[byte >> 1] = pb[n][j];
            }
        }
        const short8 ap0 = *reinterpret_cast<const short8*>(Pw + rofs0);
        const short8 ap1 = *reinterpret_cast<const short8*>(Pw + rofs1);

        // ---- PV ----
        const int kp = s0 >> 5;
        __builtin_amdgcn_s_setprio(1);
        #pragma unroll
        for (int n = 0; n < 4; ++n) {
            const size_t vr0 = (((size_t)bh * 32 + kp)     * 64 + n * 16 + (l & 15)) * 32;
            const size_t vr1 = (((size_t)bh * 32 + kp + 1) * 64 + n * 16 + (l & 15)) * 32;
            const short8 v0 = *reinterpret_cast<const short8*>(&vb_[vr0 + (l >> 4) * 8]);
            const short8 v1 = *reinterpret_cast<const short8*>(&vb_[vr1 + (l >> 4) * 8]);
            acco[n] = MFMA16(ap0, v0, acco[n]);
            acco[n] = MFMA16(ap1, v1, acco[n]);
        }
        __builtin_amdgcn_s_setprio(0);
    }

    // ---- epilogue: raw partial acc + (m, l) per row ----
    const size_t rowbase = ((size_t)(half * 64 + bh)) * 1024 + t0 + w * 16;
    #pragma unroll
    for (int j = 0; j < 4; ++j) {
        const int rr = (l >> 4) * 4 + j;
        #pragma unroll
        for (int n = 0; n < 4; ++n)
            pacc[(rowbase + rr) * 64 + n * 16 + (l & 15)] = acco[n][j];
        if ((l & 15) == 0) {
            pm[rowbase + rr] = mold[j];
            pl[rowbase + rr] = lr[j];
        }
    }
}

// ---------------------------------------------------------------------------
// Merge the two S-halves: o = (a0*w0 + a1*w1) / (l0*w0 + l1*w1), w = 2^(m-m*).
// ---------------------------------------------------------------------------
__global__ void merge_kernel(const float* __restrict__ pacc,
                             const float* __restrict__ pm,
                             const float* __restrict__ pl,
                             unsigned short* __restrict__ ohi,
                             unsigned short* __restrict__ olo)
{
    const int g = blockIdx.x * 256 + threadIdx.x;
    const int row = g >> 4;              // bh*1024 + t
    const int d4 = (g & 15) * 4;
    const int bh = row >> 10, t = row & 1023;
    const int b = bh >> 4, h = bh & 15;

    const float m0 = pm[row], m1 = pm[65536 + row];
    const float l0 = pl[row], l1 = pl[65536 + row];
    const float ms = fmaxf(m0, m1);
    const float w0 = __builtin_amdgcn_exp2f(m0 - ms);
    const float w1 = __builtin_amdgcn_exp2f(m1 - ms);
    const float den = 1.f / (l0 * w0 + l1 * w1);

    const float4 a0 = *reinterpret_cast<const float4*>(&pacc[(size_t)row * 64 + d4]);
    const float4 a1 = *reinterpret_cast<const float4*>(&pacc[(size_t)(65536 + row) * 64 + d4]);

    float o[4] = {
        (a0.x * w0 + a1.x * w1) * den,
        (a0.y * w0 + a1.y * w1) * den,
        (a0.z * w0 + a1.z * w1) * den,
        (a0.w * w0 + a1.w * w1) * den,
    };
    ushort4 vh_, vl_;
    unsigned short hh[4], ll[4];
    #pragma unroll
    for (int k = 0; k < 4; ++k) {
        hh[k] = f2bf(o[k]);
        ll[k] = f2bf(o[k] - bf2f(hh[k]));
    }
    vh_.x = hh[0]; vh_.y = hh[1]; vh_.z = hh[2]; vh_.w = hh[3];
    vl_.x = ll[0]; vl_.y = ll[1]; vl_.z = ll[2]; vl_.w = ll[3];
    const size_t oidx = ((size_t)t * B_ + b) * E_ + h * D_ + d4;
    *reinterpret_cast<ushort4*>(&ohi[oidx]) = vh_;
    *reinterpret_cast<ushort4*>(&olo[oidx]) = vl_;
}

// ---------------------------------------------------------------------------
extern "C" void kernel_launch(void* const* d_in, const int* in_sizes, int n_in,
                              void* d_out, int out_size, void* d_ws, size_t ws_size,
                              hipStream_t stream) {
    const float* query    = (const float*)d_in[0];
    const float* key      = (const float*)d_in[1];
    const float* node_key = (const float*)d_in[2];
    const float* ipw      = (const float*)d_in[3];
    const float* ipb      = (const float*)d_in[4];
    const float* out_w    = (const float*)d_in[5];
    const float* out_b    = (const float*)d_in[6];
    const float* dw_w     = (const float*)d_in[7];
    const float* dw_b     = (const float*)d_in[8];
    const unsigned char* kpm = (const unsigned char*)d_in[9];
    const unsigned char* npm = (const unsigned char*)d_in[10];
    float* out = (float*)d_out;

    char* p = (char*)d_ws;
    auto alloc = [&](size_t bytes) {
        char* r = p;
        p += (bytes + 255) & ~(size_t)255;
        return r;
    };
    // xq..pad region (32 MiB) is reused as pacc after proj_mfma has consumed it
    unsigned short* xq    = (unsigned short*)alloc((size_t)4096 * 1024 * 2);
    unsigned short* xk    = (unsigned short*)alloc((size_t)4096 * 1024 * 2);
    unsigned short* xn    = (unsigned short*)alloc((size_t)4096 * 1024 * 2);
    unsigned short* wbf   = (unsigned short*)alloc((size_t)3072 * 1024 * 2);
    (void)alloc((size_t)2 * 1024 * 1024);   // pad so pacc (32 MiB) fits over xq..here
    unsigned short* wohi  = (unsigned short*)alloc((size_t)1024 * 1024 * 2);
    unsigned short* wolo  = (unsigned short*)alloc((size_t)1024 * 1024 * 2);
    unsigned short* qb    = (unsigned short*)alloc((size_t)64 * 1024 * 64 * 2);
    unsigned short* kb_   = (unsigned short*)alloc((size_t)64 * 1024 * 64 * 2);
    unsigned short* nkb   = (unsigned short*)alloc((size_t)64 * 1024 * 64 * 2);
    unsigned short* vtb   = (unsigned short*)alloc((size_t)64 * 1024 * 64 * 2);
    unsigned short* nvtb  = (unsigned short*)alloc((size_t)64 * 1024 * 64 * 2);
    unsigned short* ohi   = (unsigned short*)alloc((size_t)4096 * 1024 * 2);
    unsigned short* olo   = (unsigned short*)alloc((size_t)4096 * 1024 * 2);
    float*          dwb   = (float*)alloc((size_t)4096 * 16 * 4);
    float*          pm    = (float*)alloc((size_t)2 * 65536 * 4);
    float*          pl    = (float*)alloc((size_t)2 * 65536 * 4);
    float*          pacc  = (float*)xq;     // 2*64*1024*64 f32 = 32 MiB overlay

    const dim3 blk(256);

    // 1) conversions
    f2bf_kernel<<<dim3(4096), blk, 0, stream>>>(query,    xq, 4194304, 4194304);
    f2bf_kernel<<<dim3(4096), blk, 0, stream>>>(key,      xk, 4194304, 4194304);
    f2bf_kernel<<<dim3(4096), blk, 0, stream>>>(node_key, xn, 4190208, 4194304);
    f2bf_kernel<<<dim3(3072), blk, 0, stream>>>(ipw,      wbf, 3145728, 3145728);
    f2bf_hilo_kernel<<<dim3(1024), blk, 0, stream>>>(out_w, wohi, wolo, 1048576);

    // 2) dw gate
    dw_kernel<<<dim3(M_ * B_), blk, 0, stream>>>(node_key, dw_w, dw_b, dwb);

    // 3) fused input projections
    proj_mfma<<<dim3(8, 32, 5), blk, 0, stream>>>(xq, xk, xn, wbf, ipb, dwb,
                                                  qb, kb_, vtb, nkb, nvtb);

    // 4) attention, split-S (overwrites xq-region with pacc)
    attn_mfma<<<dim3(64, 16, 2), blk, 0, stream>>>(qb, kb_, nkb, vtb, nvtb,
                                                   kpm, npm, pacc, pm, pl);

    // 5) merge halves -> hi/lo bf16 o
    merge_kernel<<<dim3(4096), blk, 0, stream>>>(pacc, pm, pl, ohi, olo);

    // 6) output projection (hi/lo 3-term) -> d_out fp32
    outproj_mfma<<<dim3(8, 32), blk, 0, stream>>>(ohi, olo, wohi, wolo, out_b, out);
}

// Round 6
// 300.921 us; speedup vs baseline: 1.5111x; 1.2302x over previous
//
#include <hip/hip_runtime.h>
#include <cstdint>
#include <cstddef>

using short8 = __attribute__((ext_vector_type(8))) short;
using f32x4  = __attribute__((ext_vector_type(4))) float;

constexpr int T_ = 1024;
constexpr int N_ = 1024;
constexpr int M_ = 1023;
constexpr int B_ = 4;
constexpr int E_ = 1024;
constexpr int H_ = 16;
constexpr int D_ = 64;

#define MFMA16(a, b, c) __builtin_amdgcn_mfma_f32_16x16x32_bf16((a), (b), (c), 0, 0, 0)

__device__ __forceinline__ unsigned short f2bf(float f) {
    unsigned int u = __float_as_uint(f);
    u += 0x7FFF + ((u >> 16) & 1);          // round-to-nearest-even
    return (unsigned short)(u >> 16);
}
__device__ __forceinline__ float bf2f(unsigned short s) {
    return __uint_as_float(((unsigned int)s) << 16);
}

// global -> LDS direct copy, 16 B per lane. LDS dest must be wave-uniform;
// HW writes lds_base + lane*16. Global source IS per-lane -> swizzles are
// applied by permuting the SOURCE address (m173), LDS stays linear.
typedef __attribute__((address_space(1))) const unsigned char gc_byte;
typedef __attribute__((address_space(3))) unsigned char lds_byte;
__device__ __forceinline__ void gload16(const void* g, void* lds) {
    __builtin_amdgcn_global_load_lds((gc_byte*)(uintptr_t)g,
                                     (lds_byte*)(unsigned int)(uintptr_t)lds,
                                     16, 0, 0);
}

// ---------------------------------------------------------------------------
// fp32 -> bf16 conversion, with zero-padding from n..npad (npad % 4 == 0)
// ---------------------------------------------------------------------------
__global__ void f2bf_kernel(const float* __restrict__ src,
                            unsigned short* __restrict__ dst, int n, int npad)
{
    int i = (blockIdx.x * 256 + threadIdx.x) * 4;
    if (i >= npad) return;
    if (i + 4 <= n) {
        const float4 v = *reinterpret_cast<const float4*>(src + i);
        ushort4 o;
        o.x = f2bf(v.x); o.y = f2bf(v.y); o.z = f2bf(v.z); o.w = f2bf(v.w);
        *reinterpret_cast<ushort4*>(dst + i) = o;
    } else {
        for (int k = 0; k < 4; ++k)
            dst[i + k] = (i + k < n) ? f2bf(src[i + k]) : (unsigned short)0;
    }
}

// fp32 -> (bf16 hi, bf16 lo) split.  n % 4 == 0
__global__ void f2bf_hilo_kernel(const float* __restrict__ src,
                                 unsigned short* __restrict__ dhi,
                                 unsigned short* __restrict__ dlo, int n)
{
    int i = (blockIdx.x * 256 + threadIdx.x) * 4;
    if (i >= n) return;
    const float4 v = *reinterpret_cast<const float4*>(src + i);
    float a[4] = {v.x, v.y, v.z, v.w};
    ushort4 hi, lo;
    unsigned short h[4], l[4];
    #pragma unroll
    for (int k = 0; k < 4; ++k) {
        h[k] = f2bf(a[k]);
        l[k] = f2bf(a[k] - bf2f(h[k]));
    }
    hi.x = h[0]; hi.y = h[1]; hi.z = h[2]; hi.w = h[3];
    lo.x = l[0]; lo.y = l[1]; lo.z = l[2]; lo.w = l[3];
    *reinterpret_cast<ushort4*>(dhi + i) = hi;
    *reinterpret_cast<ushort4*>(dlo + i) = lo;
}

// ---------------------------------------------------------------------------
// dw gate kernel (fp32): dw[r*H+h] = sigmoid(node_key_r . dw_w[h] + dw_b[h])
// ---------------------------------------------------------------------------
__global__ void dw_kernel(const float* __restrict__ node_key,
                          const float* __restrict__ dw_w,
                          const float* __restrict__ dw_b,
                          float* __restrict__ dwb)
{
    __shared__ float rowbuf[E_];
    const int r = blockIdx.x;
    const int tid = threadIdx.x;
    for (int idx = tid; idx < E_; idx += 256)
        rowbuf[idx] = node_key[(size_t)r * E_ + idx];
    __syncthreads();
    const int h = tid >> 4;
    const int lane = tid & 15;
    float acc = 0.f;
    const float* wrow = dw_w + (size_t)h * E_;
    for (int k = lane; k < E_; k += 16)
        acc = fmaf(rowbuf[k], wrow[k], acc);
    acc += __shfl_xor(acc, 8);
    acc += __shfl_xor(acc, 4);
    acc += __shfl_xor(acc, 2);
    acc += __shfl_xor(acc, 1);
    if (lane == 0) {
        float x = acc + dw_b[h];
        dwb[(size_t)r * H_ + h] = 1.f / (1.f + __expf(-x));
    }
}

// ---------------------------------------------------------------------------
// Fused input projections (unchanged from R3; Q-scale folds log2e for exp2).
// ---------------------------------------------------------------------------
__global__ __launch_bounds__(256) void proj_mfma(
    const unsigned short* __restrict__ xq,
    const unsigned short* __restrict__ xk,
    const unsigned short* __restrict__ xn,
    const unsigned short* __restrict__ wbf,
    const float* __restrict__ ipb,
    const float* __restrict__ dwb,
    unsigned short* __restrict__ qb,
    unsigned short* __restrict__ kb,
    unsigned short* __restrict__ vtb,
    unsigned short* __restrict__ nkb,
    unsigned short* __restrict__ nvtb)
{
    __shared__ unsigned short LDS[2][2][128 * 32];

    const unsigned short* A;
    const unsigned short* W;
    const float* bias;
    const float* dwm = nullptr;
    unsigned short* out;
    int epi;
    float scale = 1.f;
    switch (blockIdx.z) {
      case 0:  A = xq; W = wbf;           bias = ipb;        out = qb;   epi = 1; scale = 0.18033688011112042f; break;
      case 1:  A = xk; W = wbf + 1048576; bias = ipb + 1024; out = kb;   epi = 1; break;
      case 2:  A = xk; W = wbf + 2097152; bias = ipb + 2048; out = vtb;  epi = 2; break;
      case 3:  A = xn; W = wbf + 1048576; bias = ipb + 1024; out = nkb;  epi = 1; break;
      default: A = xn; W = wbf + 2097152; bias = ipb + 2048; out = nvtb; epi = 2; dwm = dwb; break;
    }

    const int tid = threadIdx.x;
    const int l = tid & 63, w = tid >> 6;
    const int brow = blockIdx.y * 128;
    const int bcol = blockIdx.x * 128;

    const int ch0 = w * 64 + l;
    const int ch1 = 256 + w * 64 + l;
    const unsigned short* gA0 = A + (size_t)(brow + (ch0 >> 2)) * E_ + (ch0 & 3) * 8;
    const unsigned short* gA1 = A + (size_t)(brow + (ch1 >> 2)) * E_ + (ch1 & 3) * 8;
    const unsigned short* gW0 = W + (size_t)(bcol + (ch0 >> 2)) * E_ + (ch0 & 3) * 8;
    const unsigned short* gW1 = W + (size_t)(bcol + (ch1 >> 2)) * E_ + (ch1 & 3) * 8;

    auto STAGE = [&](int buf, int kt) {
        gload16(gA0 + kt, &LDS[buf][0][(size_t)w * 512]);
        gload16(gA1 + kt, &LDS[buf][0][(size_t)(4 + w) * 512]);
        gload16(gW0 + kt, &LDS[buf][1][(size_t)w * 512]);
        gload16(gW1 + kt, &LDS[buf][1][(size_t)(4 + w) * 512]);
    };

    f32x4 acc[4][4];
    #pragma unroll
    for (int m = 0; m < 4; ++m)
        #pragma unroll
        for (int n = 0; n < 4; ++n)
            acc[m][n] = (f32x4){0.f, 0.f, 0.f, 0.f};

    const int wr = (w >> 1) * 64, wc = (w & 1) * 64;
    const int fr = l & 15, ko = (l >> 4) * 8;

    STAGE(0, 0);
    __syncthreads();
    for (int t = 0; t < 32; ++t) {
        const int cur = t & 1;
        if (t < 31) STAGE(cur ^ 1, (t + 1) * 32);
        short8 av[4], bv[4];
        #pragma unroll
        for (int m = 0; m < 4; ++m)
            av[m] = *reinterpret_cast<const short8*>(&LDS[cur][0][(wr + m * 16 + fr) * 32 + ko]);
        #pragma unroll
        for (int n = 0; n < 4; ++n)
            bv[n] = *reinterpret_cast<const short8*>(&LDS[cur][1][(wc + n * 16 + fr) * 32 + ko]);
        #pragma unroll
        for (int m = 0; m < 4; ++m)
            #pragma unroll
            for (int n = 0; n < 4; ++n)
                acc[m][n] = MFMA16(av[m], bv[n], acc[m][n]);
        if (t < 31) __syncthreads();
    }

    #pragma unroll
    for (int n = 0; n < 4; ++n) {
        const int c = bcol + wc + n * 16 + fr;
        const float bi = bias[c];
        #pragma unroll
        for (int m = 0; m < 4; ++m) {
            #pragma unroll
            for (int j = 0; j < 4; ++j) {
                const int r = brow + wr + m * 16 + (l >> 4) * 4 + j;
                float v = (acc[m][n][j] + bi) * scale;
                const int rn = r >> 2, b = r & 3, hh = c >> 6, dd = c & 63;
                if (epi == 1) {
                    out[((size_t)(b * H_ + hh) * 1024 + rn) * 64 + dd] = f2bf(v);
                } else {
                    if (dwm) v *= dwm[(size_t)r * H_ + hh];
                    out[(((size_t)(b * H_ + hh) * 32 + (rn >> 5)) * 64 + dd) * 32 + (rn & 31)] = f2bf(v);
                }
            }
        }
    }
}

// ---------------------------------------------------------------------------
// Output projection, hi/lo 3-term (unchanged from R3).
// ---------------------------------------------------------------------------
__global__ __launch_bounds__(256) void outproj_mfma(
    const unsigned short* __restrict__ ahi,
    const unsigned short* __restrict__ alo,
    const unsigned short* __restrict__ whi,
    const unsigned short* __restrict__ wlo,
    const float* __restrict__ out_b,
    float* __restrict__ out)
{
    __shared__ unsigned short LDS[2][4][128 * 32];

    const int tid = threadIdx.x;
    const int l = tid & 63, w = tid >> 6;
    const int brow = blockIdx.y * 128;
    const int bcol = blockIdx.x * 128;

    const int ch0 = w * 64 + l;
    const int ch1 = 256 + w * 64 + l;
    const size_t ra0 = (size_t)(brow + (ch0 >> 2)) * E_ + (ch0 & 3) * 8;
    const size_t ra1 = (size_t)(brow + (ch1 >> 2)) * E_ + (ch1 & 3) * 8;
    const size_t rb0 = (size_t)(bcol + (ch0 >> 2)) * E_ + (ch0 & 3) * 8;
    const size_t rb1 = (size_t)(bcol + (ch1 >> 2)) * E_ + (ch1 & 3) * 8;

    auto STAGE = [&](int buf, int kt) {
        gload16(ahi + ra0 + kt, &LDS[buf][0][(size_t)w * 512]);
        gload16(ahi + ra1 + kt, &LDS[buf][0][(size_t)(4 + w) * 512]);
        gload16(alo + ra0 + kt, &LDS[buf][1][(size_t)w * 512]);
        gload16(alo + ra1 + kt, &LDS[buf][1][(size_t)(4 + w) * 512]);
        gload16(whi + rb0 + kt, &LDS[buf][2][(size_t)w * 512]);
        gload16(whi + rb1 + kt, &LDS[buf][2][(size_t)(4 + w) * 512]);
        gload16(wlo + rb0 + kt, &LDS[buf][3][(size_t)w * 512]);
        gload16(wlo + rb1 + kt, &LDS[buf][3][(size_t)(4 + w) * 512]);
    };

    f32x4 acc[4][4];
    #pragma unroll
    for (int m = 0; m < 4; ++m)
        #pragma unroll
        for (int n = 0; n < 4; ++n)
            acc[m][n] = (f32x4){0.f, 0.f, 0.f, 0.f};

    const int wr = (w >> 1) * 64, wc = (w & 1) * 64;
    const int fr = l & 15, ko = (l >> 4) * 8;

    STAGE(0, 0);
    __syncthreads();
    for (int t = 0; t < 32; ++t) {
        const int cur = t & 1;
        if (t < 31) STAGE(cur ^ 1, (t + 1) * 32);
        short8 ah[4], al[4], bh[4], bl[4];
        #pragma unroll
        for (int m = 0; m < 4; ++m) {
            ah[m] = *reinterpret_cast<const short8*>(&LDS[cur][0][(wr + m * 16 + fr) * 32 + ko]);
            al[m] = *reinterpret_cast<const short8*>(&LDS[cur][1][(wr + m * 16 + fr) * 32 + ko]);
        }
        #pragma unroll
        for (int n = 0; n < 4; ++n) {
            bh[n] = *reinterpret_cast<const short8*>(&LDS[cur][2][(wc + n * 16 + fr) * 32 + ko]);
            bl[n] = *reinterpret_cast<const short8*>(&LDS[cur][3][(wc + n * 16 + fr) * 32 + ko]);
        }
        #pragma unroll
        for (int m = 0; m < 4; ++m)
            #pragma unroll
            for (int n = 0; n < 4; ++n) {
                acc[m][n] = MFMA16(ah[m], bh[n], acc[m][n]);
                acc[m][n] = MFMA16(al[m], bh[n], acc[m][n]);
                acc[m][n] = MFMA16(ah[m], bl[n], acc[m][n]);
            }
        if (t < 31) __syncthreads();
    }

    #pragma unroll
    for (int n = 0; n < 4; ++n) {
        const int c = bcol + wc + n * 16 + fr;
        const float bi = out_b[c];
        #pragma unroll
        for (int m = 0; m < 4; ++m)
            #pragma unroll
            for (int j = 0; j < 4; ++j) {
                const int r = brow + wr + m * 16 + (l >> 4) * 4 + j;
                out[(size_t)r * E_ + c] = acc[m][n][j] + bi;
            }
    }
}

// ---------------------------------------------------------------------------
// MFMA flash attention, SPLIT-S, LDS-staged K/V (R6):
// Per 64-kv tile, K (row-major, XOR-swizzled via pre-swizzled global source)
// and V (panel [kgroup8][d64][k8]) are staged global->LDS with
// global_load_lds double-buffer; one __syncthreads per tile (compiler
// drains vmcnt). Removes 4x redundant per-wave L2 reads and hides latency.
// Occupancy is reg-capped at 4 waves/SIMD (acc regs push waves past the
// 64-reg granule) -> do NOT add min-waves launch bounds (R4 spill lesson).
// ---------------------------------------------------------------------------
__global__ __launch_bounds__(256) void attn_mfma(
    const unsigned short* __restrict__ qbf,
    const unsigned short* __restrict__ kbf,
    const unsigned short* __restrict__ nkbf,
    const unsigned short* __restrict__ vtb,
    const unsigned short* __restrict__ nvtb,
    const unsigned char* __restrict__ kpm,
    const unsigned char* __restrict__ npm,
    float* __restrict__ pacc,
    float* __restrict__ pm,
    float* __restrict__ pl)
{
    __shared__ unsigned short Kl[2][64 * 64];   // 8 KB each, swizzled rows
    __shared__ unsigned short Vl[2][64 * 64];   // 8 KB each, [kg][d][k8]
    __shared__ unsigned short maskB[1024];      // bf16 additive mask
    __shared__ int tmask[16];
    __shared__ unsigned short Pl[4][16 * 64];   // per-wave P, XOR-swizzled

    const int tid = threadIdx.x;
    const int l = tid & 63, w = tid >> 6;
    const int bh = blockIdx.x, b = bh >> 4;
    const int t0 = blockIdx.y * 64;
    const int half = blockIdx.z;

    const unsigned short* kb_ = half ? nkbf : kbf;   // [bh][1024][64] rows
    const unsigned short* vb_ = half ? nvtb : vtb;   // [bh][32][64][32] panels

    if (tid < 16) tmask[tid] = 0;
    __syncthreads();
    {
        const unsigned short negbf = f2bf(-60000.f);
        for (int s = tid; s < 1024; s += 256) {
            int masked;
            if (half == 0) masked = kpm[(size_t)b * N_ + s] ? 1 : 0;
            else           masked = (s < M_ && !npm[(size_t)b * M_ + s]) ? 0 : 1;
            maskB[s] = masked ? negbf : (unsigned short)0;
            if (masked) atomicOr(&tmask[s >> 6], 1);
        }
    }

    // staging: 512 chunks each for K and V; thread handles chunks tid, 256+tid
    auto STAGE = [&](int buf, int s0) {
        #pragma unroll
        for (int u = 0; u < 2; ++u) {
            const int c = u * 256 + tid;
            // K: logical (row = c>>3, colbyte (c&7)*16), source pre-swizzled
            const int krow = c >> 3;
            const int kcol = ((c & 7) * 16) ^ ((krow & 7) << 4);
            gload16((const unsigned char*)kb_ +
                        ((size_t)(bh * 1024 + s0 + krow) * 64) * 2 + kcol,
                    (unsigned char*)&Kl[buf][0] + c * 16);
            // V: LDS [kg = c>>6][d = c&63][k 0..7]; source = panel layout
            const int kg = c >> 6;
            const int dd = c & 63;
            const int kv = s0 + kg * 8;
            const int kp = kv >> 5;
            gload16((const unsigned char*)vb_ +
                        (((size_t)(bh * 32 + kp) * 64 + dd) * 32 + (kv & 31)) * 2,
                    (unsigned char*)&Vl[buf][0] + c * 16);
        }
    };

    const int qrow = t0 + w * 16 + (l & 15);
    const short8 aq0 = *reinterpret_cast<const short8*>(&qbf[((size_t)bh * T_ + qrow) * 64 + (l >> 4) * 8]);
    const short8 aq1 = *reinterpret_cast<const short8*>(&qbf[((size_t)bh * T_ + qrow) * 64 + 32 + (l >> 4) * 8]);

    float mold[4], lr[4];
    #pragma unroll
    for (int j = 0; j < 4; ++j) { mold[j] = -30000.f; lr[j] = 0.f; }
    f32x4 acco[4];
    #pragma unroll
    for (int n = 0; n < 4; ++n) acco[n] = (f32x4){0.f, 0.f, 0.f, 0.f};

    unsigned short* const Pw = &Pl[w][0];
    const int prow_r = l & 15;
    const int rofs0 = ((prow_r * 128 + (l >> 4) * 16) ^ ((prow_r & 7) << 4)) >> 1;
    const int rofs1 = ((prow_r * 128 + 64 + (l >> 4) * 16) ^ ((prow_r & 7) << 4)) >> 1;

    // LDS fragment read offsets (bytes)
    const int g = l >> 4;
    const int ksw = (l & 7) << 4;
    const int kb0 = (l & 15) * 128 + ((g * 16) ^ ksw);        // + n*2048
    const int kb1 = (l & 15) * 128 + ((64 + g * 16) ^ ksw);   // + n*2048
    const int vb0 = g * 1024 + (l & 15) * 16;                 // + n*256 (+4096 for v1)

    STAGE(0, 0);
    __syncthreads();    // drains vmcnt(0): buf0 staged; mask filled

    for (int it = 0; it < 16; ++it) {
        const int s0 = it * 64;
        const int cur = it & 1;
        if (it < 15) STAGE(cur ^ 1, s0 + 64);

        const unsigned char* const Kc = (const unsigned char*)&Kl[cur][0];
        const unsigned char* const Vc = (const unsigned char*)&Vl[cur][0];

        // ---- QK^T from LDS ----
        f32x4 accs[4];
        #pragma unroll
        for (int n = 0; n < 4; ++n) accs[n] = (f32x4){0.f, 0.f, 0.f, 0.f};
        __builtin_amdgcn_s_setprio(1);
        #pragma unroll
        for (int n = 0; n < 4; ++n) {
            const short8 k0 = *reinterpret_cast<const short8*>(Kc + n * 2048 + kb0);
            const short8 k1 = *reinterpret_cast<const short8*>(Kc + n * 2048 + kb1);
            accs[n] = MFMA16(aq0, k0, accs[n]);
            accs[n] = MFMA16(aq1, k1, accs[n]);
        }
        __builtin_amdgcn_s_setprio(0);

        // ---- mask in-place (only if tile has any masked col) ----
        if (tmask[s0 >> 6]) {
            #pragma unroll
            for (int n = 0; n < 4; ++n) {
                const float mz = bf2f(maskB[s0 + n * 16 + (l & 15)]);
                #pragma unroll
                for (int j = 0; j < 4; ++j) accs[n][j] += mz;
            }
        }

        // ---- row max ----
        float mx[4] = {-60000.f, -60000.f, -60000.f, -60000.f};
        #pragma unroll
        for (int n = 0; n < 4; ++n)
            #pragma unroll
            for (int j = 0; j < 4; ++j) mx[j] = fmaxf(mx[j], accs[n][j]);
        #pragma unroll
        for (int j = 0; j < 4; ++j) {
            mx[j] = fmaxf(mx[j], __shfl_xor(mx[j], 1));
            mx[j] = fmaxf(mx[j], __shfl_xor(mx[j], 2));
            mx[j] = fmaxf(mx[j], __shfl_xor(mx[j], 4));
            mx[j] = fmaxf(mx[j], __shfl_xor(mx[j], 8));
        }

        // ---- defer-max ----
        int need = 0;
        #pragma unroll
        for (int j = 0; j < 4; ++j) need |= (mx[j] > mold[j] + 8.f);
        if (__any(need)) {
            #pragma unroll
            for (int j = 0; j < 4; ++j) {
                const float mn = fmaxf(mold[j], mx[j]);
                const float f = __builtin_amdgcn_exp2f(mold[j] - mn);
                mold[j] = mn;
                lr[j] *= f;
                #pragma unroll
                for (int n = 0; n < 4; ++n) acco[n][j] *= f;
            }
        }

        // ---- P = exp2(s - m); masked entries underflow to exact 0 ----
        float ps[4] = {0.f, 0.f, 0.f, 0.f};
        unsigned short pb[4][4];
        #pragma unroll
        for (int n = 0; n < 4; ++n)
            #pragma unroll
            for (int j = 0; j < 4; ++j) {
                const float p = __builtin_amdgcn_exp2f(accs[n][j] - mold[j]);
                pb[n][j] = f2bf(p);
                ps[j] += p;
            }
        #pragma unroll
        for (int j = 0; j < 4; ++j) {
            float p = ps[j];
            p += __shfl_xor(p, 1);
            p += __shfl_xor(p, 2);
            p += __shfl_xor(p, 4);
            p += __shfl_xor(p, 8);
            lr[j] += p;
        }

        // ---- P -> LDS (swizzled) -> A-frags ----
        #pragma unroll
        for (int j = 0; j < 4; ++j) {
            const int prow = (l >> 4) * 4 + j;
            const int rb = prow * 128;
            const int sw = (prow & 7) << 4;
            #pragma unroll
            for (int n = 0; n < 4; ++n) {
                const int byte = (rb + (n * 16 + (l & 15)) * 2) ^ sw;
                Pw[byte >> 1] = pb[n][j];
            }
        }
        const short8 ap0 = *reinterpret_cast<const short8*>(Pw + rofs0);
        const short8 ap1 = *reinterpret_cast<const short8*>(Pw + rofs1);

        // ---- PV from LDS ----
        __builtin_amdgcn_s_setprio(1);
        #pragma unroll
        for (int n = 0; n < 4; ++n) {
            const short8 v0 = *reinterpret_cast<const short8*>(Vc + n * 256 + vb0);
            const short8 v1 = *reinterpret_cast<const short8*>(Vc + 4096 + n * 256 + vb0);
            acco[n] = MFMA16(ap0, v0, acco[n]);
            acco[n] = MFMA16(ap1, v1, acco[n]);
        }
        __builtin_amdgcn_s_setprio(0);

        __syncthreads();    // next buf staged (vmcnt drained); cur free to reuse
    }

    // ---- epilogue: raw partial acc + (m, l) per row ----
    const size_t rowbase = ((size_t)(half * 64 + bh)) * 1024 + t0 + w * 16;
    #pragma unroll
    for (int j = 0; j < 4; ++j) {
        const int rr = (l >> 4) * 4 + j;
        #pragma unroll
        for (int n = 0; n < 4; ++n)
            pacc[(rowbase + rr) * 64 + n * 16 + (l & 15)] = acco[n][j];
        if ((l & 15) == 0) {
            pm[rowbase + rr] = mold[j];
            pl[rowbase + rr] = lr[j];
        }
    }
}

// ---------------------------------------------------------------------------
// Merge the two S-halves: o = (a0*w0 + a1*w1) / (l0*w0 + l1*w1), w = 2^(m-m*).
// ---------------------------------------------------------------------------
__global__ void merge_kernel(const float* __restrict__ pacc,
                             const float* __restrict__ pm,
                             const float* __restrict__ pl,
                             unsigned short* __restrict__ ohi,
                             unsigned short* __restrict__ olo)
{
    const int g = blockIdx.x * 256 + threadIdx.x;
    const int row = g >> 4;              // bh*1024 + t
    const int d4 = (g & 15) * 4;
    const int bh = row >> 10, t = row & 1023;
    const int b = bh >> 4, h = bh & 15;

    const float m0 = pm[row], m1 = pm[65536 + row];
    const float l0 = pl[row], l1 = pl[65536 + row];
    const float ms = fmaxf(m0, m1);
    const float w0 = __builtin_amdgcn_exp2f(m0 - ms);
    const float w1 = __builtin_amdgcn_exp2f(m1 - ms);
    const float den = 1.f / (l0 * w0 + l1 * w1);

    const float4 a0 = *reinterpret_cast<const float4*>(&pacc[(size_t)row * 64 + d4]);
    const float4 a1 = *reinterpret_cast<const float4*>(&pacc[(size_t)(65536 + row) * 64 + d4]);

    float o[4] = {
        (a0.x * w0 + a1.x * w1) * den,
        (a0.y * w0 + a1.y * w1) * den,
        (a0.z * w0 + a1.z * w1) * den,
        (a0.w * w0 + a1.w * w1) * den,
    };
    ushort4 vh_, vl_;
    unsigned short hh[4], ll[4];
    #pragma unroll
    for (int k = 0; k < 4; ++k) {
        hh[k] = f2bf(o[k]);
        ll[k] = f2bf(o[k] - bf2f(hh[k]));
    }
    vh_.x = hh[0]; vh_.y = hh[1]; vh_.z = hh[2]; vh_.w = hh[3];
    vl_.x = ll[0]; vl_.y = ll[1]; vl_.z = ll[2]; vl_.w = ll[3];
    const size_t oidx = ((size_t)t * B_ + b) * E_ + h * D_ + d4;
    *reinterpret_cast<ushort4*>(&ohi[oidx]) = vh_;
    *reinterpret_cast<ushort4*>(&olo[oidx]) = vl_;
}

// ---------------------------------------------------------------------------
extern "C" void kernel_launch(void* const* d_in, const int* in_sizes, int n_in,
                              void* d_out, int out_size, void* d_ws, size_t ws_size,
                              hipStream_t stream) {
    const float* query    = (const float*)d_in[0];
    const float* key      = (const float*)d_in[1];
    const float* node_key = (const float*)d_in[2];
    const float* ipw      = (const float*)d_in[3];
    const float* ipb      = (const float*)d_in[4];
    const float* out_w    = (const float*)d_in[5];
    const float* out_b    = (const float*)d_in[6];
    const float* dw_w     = (const float*)d_in[7];
    const float* dw_b     = (const float*)d_in[8];
    const unsigned char* kpm = (const unsigned char*)d_in[9];
    const unsigned char* npm = (const unsigned char*)d_in[10];
    float* out = (float*)d_out;

    char* p = (char*)d_ws;
    auto alloc = [&](size_t bytes) {
        char* r = p;
        p += (bytes + 255) & ~(size_t)255;
        return r;
    };
    // xq..pad region (32 MiB) is reused as pacc after proj_mfma has consumed it
    unsigned short* xq    = (unsigned short*)alloc((size_t)4096 * 1024 * 2);
    unsigned short* xk    = (unsigned short*)alloc((size_t)4096 * 1024 * 2);
    unsigned short* xn    = (unsigned short*)alloc((size_t)4096 * 1024 * 2);
    unsigned short* wbf   = (unsigned short*)alloc((size_t)3072 * 1024 * 2);
    (void)alloc((size_t)2 * 1024 * 1024);   // pad so pacc (32 MiB) fits over xq..here
    unsigned short* wohi  = (unsigned short*)alloc((size_t)1024 * 1024 * 2);
    unsigned short* wolo  = (unsigned short*)alloc((size_t)1024 * 1024 * 2);
    unsigned short* qb    = (unsigned short*)alloc((size_t)64 * 1024 * 64 * 2);
    unsigned short* kb_   = (unsigned short*)alloc((size_t)64 * 1024 * 64 * 2);
    unsigned short* nkb   = (unsigned short*)alloc((size_t)64 * 1024 * 64 * 2);
    unsigned short* vtb   = (unsigned short*)alloc((size_t)64 * 1024 * 64 * 2);
    unsigned short* nvtb  = (unsigned short*)alloc((size_t)64 * 1024 * 64 * 2);
    unsigned short* ohi   = (unsigned short*)alloc((size_t)4096 * 1024 * 2);
    unsigned short* olo   = (unsigned short*)alloc((size_t)4096 * 1024 * 2);
    float*          dwb   = (float*)alloc((size_t)4096 * 16 * 4);
    float*          pm    = (float*)alloc((size_t)2 * 65536 * 4);
    float*          pl    = (float*)alloc((size_t)2 * 65536 * 4);
    float*          pacc  = (float*)xq;     // 2*64*1024*64 f32 = 32 MiB overlay

    const dim3 blk(256);

    // 1) conversions
    f2bf_kernel<<<dim3(4096), blk, 0, stream>>>(query,    xq, 4194304, 4194304);
    f2bf_kernel<<<dim3(4096), blk, 0, stream>>>(key,      xk, 4194304, 4194304);
    f2bf_kernel<<<dim3(4096), blk, 0, stream>>>(node_key, xn, 4190208, 4194304);
    f2bf_kernel<<<dim3(3072), blk, 0, stream>>>(ipw,      wbf, 3145728, 3145728);
    f2bf_hilo_kernel<<<dim3(1024), blk, 0, stream>>>(out_w, wohi, wolo, 1048576);

    // 2) dw gate
    dw_kernel<<<dim3(M_ * B_), blk, 0, stream>>>(node_key, dw_w, dw_b, dwb);

    // 3) fused input projections
    proj_mfma<<<dim3(8, 32, 5), blk, 0, stream>>>(xq, xk, xn, wbf, ipb, dwb,
                                                  qb, kb_, vtb, nkb, nvtb);

    // 4) attention, split-S, LDS-staged K/V (overwrites xq-region with pacc)
    attn_mfma<<<dim3(64, 16, 2), blk, 0, stream>>>(qb, kb_, nkb, vtb, nvtb,
                                                   kpm, npm, pacc, pm, pl);

    // 5) merge halves -> hi/lo bf16 o
    merge_kernel<<<dim3(4096), blk, 0, stream>>>(pacc, pm, pl, ohi, olo);

    // 6) output projection (hi/lo 3-term) -> d_out fp32
    outproj_mfma<<<dim3(8, 32), blk, 0, stream>>>(ohi, olo, wohi, wolo, out_b, out);
}

// Round 7
// 269.764 us; speedup vs baseline: 1.6857x; 1.1155x over previous
//
#include <hip/hip_runtime.h>
#include <cstdint>
#include <cstddef>

using short8 = __attribute__((ext_vector_type(8))) short;
using f32x4  = __attribute__((ext_vector_type(4))) float;

constexpr int T_ = 1024;
constexpr int N_ = 1024;
constexpr int M_ = 1023;
constexpr int B_ = 4;
constexpr int E_ = 1024;
constexpr int H_ = 16;
constexpr int D_ = 64;

#define MFMA16(a, b, c) __builtin_amdgcn_mfma_f32_16x16x32_bf16((a), (b), (c), 0, 0, 0)

__device__ __forceinline__ unsigned short f2bf(float f) {
    unsigned int u = __float_as_uint(f);
    u += 0x7FFF + ((u >> 16) & 1);          // round-to-nearest-even
    return (unsigned short)(u >> 16);
}
__device__ __forceinline__ float bf2f(unsigned short s) {
    return __uint_as_float(((unsigned int)s) << 16);
}

// HW packed fp32->bf16 pair conversion (RNE). lo -> bits[15:0], hi -> [31:16].
__device__ __forceinline__ unsigned int cvt_pk_bf16(float lo, float hi) {
    unsigned int r;
    asm("v_cvt_pk_bf16_f32 %0, %1, %2" : "=v"(r) : "v"(lo), "v"(hi));
    return r;
}

// global -> LDS direct copy, 16 B per lane. LDS dest must be wave-uniform;
// HW writes lds_base + lane*16. Global source IS per-lane -> swizzles are
// applied by permuting the SOURCE address (m173), LDS stays linear.
typedef __attribute__((address_space(1))) const unsigned char gc_byte;
typedef __attribute__((address_space(3))) unsigned char lds_byte;
__device__ __forceinline__ void gload16(const void* g, void* lds) {
    __builtin_amdgcn_global_load_lds((gc_byte*)(uintptr_t)g,
                                     (lds_byte*)(unsigned int)(uintptr_t)lds,
                                     16, 0, 0);
}

// ---------------------------------------------------------------------------
// fp32 -> bf16 conversion, with zero-padding from n..npad (npad % 4 == 0)
// ---------------------------------------------------------------------------
__global__ void f2bf_kernel(const float* __restrict__ src,
                            unsigned short* __restrict__ dst, int n, int npad)
{
    int i = (blockIdx.x * 256 + threadIdx.x) * 4;
    if (i >= npad) return;
    if (i + 4 <= n) {
        const float4 v = *reinterpret_cast<const float4*>(src + i);
        ushort4 o;
        o.x = f2bf(v.x); o.y = f2bf(v.y); o.z = f2bf(v.z); o.w = f2bf(v.w);
        *reinterpret_cast<ushort4*>(dst + i) = o;
    } else {
        for (int k = 0; k < 4; ++k)
            dst[i + k] = (i + k < n) ? f2bf(src[i + k]) : (unsigned short)0;
    }
}

// fp32 -> (bf16 hi, bf16 lo) split.  n % 4 == 0
__global__ void f2bf_hilo_kernel(const float* __restrict__ src,
                                 unsigned short* __restrict__ dhi,
                                 unsigned short* __restrict__ dlo, int n)
{
    int i = (blockIdx.x * 256 + threadIdx.x) * 4;
    if (i >= n) return;
    const float4 v = *reinterpret_cast<const float4*>(src + i);
    float a[4] = {v.x, v.y, v.z, v.w};
    ushort4 hi, lo;
    unsigned short h[4], l[4];
    #pragma unroll
    for (int k = 0; k < 4; ++k) {
        h[k] = f2bf(a[k]);
        l[k] = f2bf(a[k] - bf2f(h[k]));
    }
    hi.x = h[0]; hi.y = h[1]; hi.z = h[2]; hi.w = h[3];
    lo.x = l[0]; lo.y = l[1]; lo.z = l[2]; lo.w = l[3];
    *reinterpret_cast<ushort4*>(dhi + i) = hi;
    *reinterpret_cast<ushort4*>(dlo + i) = lo;
}

// ---------------------------------------------------------------------------
// dw gate kernel (fp32): dw[r*H+h] = sigmoid(node_key_r . dw_w[h] + dw_b[h])
// ---------------------------------------------------------------------------
__global__ void dw_kernel(const float* __restrict__ node_key,
                          const float* __restrict__ dw_w,
                          const float* __restrict__ dw_b,
                          float* __restrict__ dwb)
{
    __shared__ float rowbuf[E_];
    const int r = blockIdx.x;
    const int tid = threadIdx.x;
    for (int idx = tid; idx < E_; idx += 256)
        rowbuf[idx] = node_key[(size_t)r * E_ + idx];
    __syncthreads();
    const int h = tid >> 4;
    const int lane = tid & 15;
    float acc = 0.f;
    const float* wrow = dw_w + (size_t)h * E_;
    for (int k = lane; k < E_; k += 16)
        acc = fmaf(rowbuf[k], wrow[k], acc);
    acc += __shfl_xor(acc, 8);
    acc += __shfl_xor(acc, 4);
    acc += __shfl_xor(acc, 2);
    acc += __shfl_xor(acc, 1);
    if (lane == 0) {
        float x = acc + dw_b[h];
        dwb[(size_t)r * H_ + h] = 1.f / (1.f + __expf(-x));
    }
}

// ---------------------------------------------------------------------------
// Fused input projections (unchanged from R3; Q-scale folds log2e for exp2).
// ---------------------------------------------------------------------------
__global__ __launch_bounds__(256) void proj_mfma(
    const unsigned short* __restrict__ xq,
    const unsigned short* __restrict__ xk,
    const unsigned short* __restrict__ xn,
    const unsigned short* __restrict__ wbf,
    const float* __restrict__ ipb,
    const float* __restrict__ dwb,
    unsigned short* __restrict__ qb,
    unsigned short* __restrict__ kb,
    unsigned short* __restrict__ vtb,
    unsigned short* __restrict__ nkb,
    unsigned short* __restrict__ nvtb)
{
    __shared__ unsigned short LDS[2][2][128 * 32];

    const unsigned short* A;
    const unsigned short* W;
    const float* bias;
    const float* dwm = nullptr;
    unsigned short* out;
    int epi;
    float scale = 1.f;
    switch (blockIdx.z) {
      case 0:  A = xq; W = wbf;           bias = ipb;        out = qb;   epi = 1; scale = 0.18033688011112042f; break;
      case 1:  A = xk; W = wbf + 1048576; bias = ipb + 1024; out = kb;   epi = 1; break;
      case 2:  A = xk; W = wbf + 2097152; bias = ipb + 2048; out = vtb;  epi = 2; break;
      case 3:  A = xn; W = wbf + 1048576; bias = ipb + 1024; out = nkb;  epi = 1; break;
      default: A = xn; W = wbf + 2097152; bias = ipb + 2048; out = nvtb; epi = 2; dwm = dwb; break;
    }

    const int tid = threadIdx.x;
    const int l = tid & 63, w = tid >> 6;
    const int brow = blockIdx.y * 128;
    const int bcol = blockIdx.x * 128;

    const int ch0 = w * 64 + l;
    const int ch1 = 256 + w * 64 + l;
    const unsigned short* gA0 = A + (size_t)(brow + (ch0 >> 2)) * E_ + (ch0 & 3) * 8;
    const unsigned short* gA1 = A + (size_t)(brow + (ch1 >> 2)) * E_ + (ch1 & 3) * 8;
    const unsigned short* gW0 = W + (size_t)(bcol + (ch0 >> 2)) * E_ + (ch0 & 3) * 8;
    const unsigned short* gW1 = W + (size_t)(bcol + (ch1 >> 2)) * E_ + (ch1 & 3) * 8;

    auto STAGE = [&](int buf, int kt) {
        gload16(gA0 + kt, &LDS[buf][0][(size_t)w * 512]);
        gload16(gA1 + kt, &LDS[buf][0][(size_t)(4 + w) * 512]);
        gload16(gW0 + kt, &LDS[buf][1][(size_t)w * 512]);
        gload16(gW1 + kt, &LDS[buf][1][(size_t)(4 + w) * 512]);
    };

    f32x4 acc[4][4];
    #pragma unroll
    for (int m = 0; m < 4; ++m)
        #pragma unroll
        for (int n = 0; n < 4; ++n)
            acc[m][n] = (f32x4){0.f, 0.f, 0.f, 0.f};

    const int wr = (w >> 1) * 64, wc = (w & 1) * 64;
    const int fr = l & 15, ko = (l >> 4) * 8;

    STAGE(0, 0);
    __syncthreads();
    for (int t = 0; t < 32; ++t) {
        const int cur = t & 1;
        if (t < 31) STAGE(cur ^ 1, (t + 1) * 32);
        short8 av[4], bv[4];
        #pragma unroll
        for (int m = 0; m < 4; ++m)
            av[m] = *reinterpret_cast<const short8*>(&LDS[cur][0][(wr + m * 16 + fr) * 32 + ko]);
        #pragma unroll
        for (int n = 0; n < 4; ++n)
            bv[n] = *reinterpret_cast<const short8*>(&LDS[cur][1][(wc + n * 16 + fr) * 32 + ko]);
        #pragma unroll
        for (int m = 0; m < 4; ++m)
            #pragma unroll
            for (int n = 0; n < 4; ++n)
                acc[m][n] = MFMA16(av[m], bv[n], acc[m][n]);
        if (t < 31) __syncthreads();
    }

    #pragma unroll
    for (int n = 0; n < 4; ++n) {
        const int c = bcol + wc + n * 16 + fr;
        const float bi = bias[c];
        #pragma unroll
        for (int m = 0; m < 4; ++m) {
            #pragma unroll
            for (int j = 0; j < 4; ++j) {
                const int r = brow + wr + m * 16 + (l >> 4) * 4 + j;
                float v = (acc[m][n][j] + bi) * scale;
                const int rn = r >> 2, b = r & 3, hh = c >> 6, dd = c & 63;
                if (epi == 1) {
                    out[((size_t)(b * H_ + hh) * 1024 + rn) * 64 + dd] = f2bf(v);
                } else {
                    if (dwm) v *= dwm[(size_t)r * H_ + hh];
                    out[(((size_t)(b * H_ + hh) * 32 + (rn >> 5)) * 64 + dd) * 32 + (rn & 31)] = f2bf(v);
                }
            }
        }
    }
}

// ---------------------------------------------------------------------------
// Output projection, hi/lo 3-term (unchanged from R3).
// ---------------------------------------------------------------------------
__global__ __launch_bounds__(256) void outproj_mfma(
    const unsigned short* __restrict__ ahi,
    const unsigned short* __restrict__ alo,
    const unsigned short* __restrict__ whi,
    const unsigned short* __restrict__ wlo,
    const float* __restrict__ out_b,
    float* __restrict__ out)
{
    __shared__ unsigned short LDS[2][4][128 * 32];

    const int tid = threadIdx.x;
    const int l = tid & 63, w = tid >> 6;
    const int brow = blockIdx.y * 128;
    const int bcol = blockIdx.x * 128;

    const int ch0 = w * 64 + l;
    const int ch1 = 256 + w * 64 + l;
    const size_t ra0 = (size_t)(brow + (ch0 >> 2)) * E_ + (ch0 & 3) * 8;
    const size_t ra1 = (size_t)(brow + (ch1 >> 2)) * E_ + (ch1 & 3) * 8;
    const size_t rb0 = (size_t)(bcol + (ch0 >> 2)) * E_ + (ch0 & 3) * 8;
    const size_t rb1 = (size_t)(bcol + (ch1 >> 2)) * E_ + (ch1 & 3) * 8;

    auto STAGE = [&](int buf, int kt) {
        gload16(ahi + ra0 + kt, &LDS[buf][0][(size_t)w * 512]);
        gload16(ahi + ra1 + kt, &LDS[buf][0][(size_t)(4 + w) * 512]);
        gload16(alo + ra0 + kt, &LDS[buf][1][(size_t)w * 512]);
        gload16(alo + ra1 + kt, &LDS[buf][1][(size_t)(4 + w) * 512]);
        gload16(whi + rb0 + kt, &LDS[buf][2][(size_t)w * 512]);
        gload16(whi + rb1 + kt, &LDS[buf][2][(size_t)(4 + w) * 512]);
        gload16(wlo + rb0 + kt, &LDS[buf][3][(size_t)w * 512]);
        gload16(wlo + rb1 + kt, &LDS[buf][3][(size_t)(4 + w) * 512]);
    };

    f32x4 acc[4][4];
    #pragma unroll
    for (int m = 0; m < 4; ++m)
        #pragma unroll
        for (int n = 0; n < 4; ++n)
            acc[m][n] = (f32x4){0.f, 0.f, 0.f, 0.f};

    const int wr = (w >> 1) * 64, wc = (w & 1) * 64;
    const int fr = l & 15, ko = (l >> 4) * 8;

    STAGE(0, 0);
    __syncthreads();
    for (int t = 0; t < 32; ++t) {
        const int cur = t & 1;
        if (t < 31) STAGE(cur ^ 1, (t + 1) * 32);
        short8 ah[4], al[4], bh[4], bl[4];
        #pragma unroll
        for (int m = 0; m < 4; ++m) {
            ah[m] = *reinterpret_cast<const short8*>(&LDS[cur][0][(wr + m * 16 + fr) * 32 + ko]);
            al[m] = *reinterpret_cast<const short8*>(&LDS[cur][1][(wr + m * 16 + fr) * 32 + ko]);
        }
        #pragma unroll
        for (int n = 0; n < 4; ++n) {
            bh[n] = *reinterpret_cast<const short8*>(&LDS[cur][2][(wc + n * 16 + fr) * 32 + ko]);
            bl[n] = *reinterpret_cast<const short8*>(&LDS[cur][3][(wc + n * 16 + fr) * 32 + ko]);
        }
        #pragma unroll
        for (int m = 0; m < 4; ++m)
            #pragma unroll
            for (int n = 0; n < 4; ++n) {
                acc[m][n] = MFMA16(ah[m], bh[n], acc[m][n]);
                acc[m][n] = MFMA16(al[m], bh[n], acc[m][n]);
                acc[m][n] = MFMA16(ah[m], bl[n], acc[m][n]);
            }
        if (t < 31) __syncthreads();
    }

    #pragma unroll
    for (int n = 0; n < 4; ++n) {
        const int c = bcol + wc + n * 16 + fr;
        const float bi = out_b[c];
        #pragma unroll
        for (int m = 0; m < 4; ++m)
            #pragma unroll
            for (int j = 0; j < 4; ++j) {
                const int r = brow + wr + m * 16 + (l >> 4) * 4 + j;
                out[(size_t)r * E_ + c] = acc[m][n][j] + bi;
            }
    }
}

// ---------------------------------------------------------------------------
// MFMA flash attention, SPLIT-S, LDS-staged K/V, SWAPPED QK^T (R7):
// accs = mfma(K_frag, Q_frag) gives S^T -> each lane holds 16 scores of ONE
// q-row (q = l&15; groups g = l>>4 partition k). Row max/sum are in-lane +
// xor16/xor32; mold/lr are per-lane scalars. P is packed to bf16 pairs via
// v_cvt_pk_bf16_f32 and redistributed to PV B-frags with 16 shfl + 8 sel
// (mapping verified: word w of half h = sel_{l&32}(shfl(ppk[2h(+1)][w&1],
// (l>>4&1)*32+(l&15)+(w>>1)*16))). PV: O^T = mfma(V^T_frag, P^T_frag) with
// byte-identical V reads (panel layout IS V^T). No P-LDS -> 36.9 KB LDS ->
// 4 blocks/CU. No min-waves bound (R4 spill lesson).
// ---------------------------------------------------------------------------
__global__ __launch_bounds__(256) void attn_mfma(
    const unsigned short* __restrict__ qbf,
    const unsigned short* __restrict__ kbf,
    const unsigned short* __restrict__ nkbf,
    const unsigned short* __restrict__ vtb,
    const unsigned short* __restrict__ nvtb,
    const unsigned char* __restrict__ kpm,
    const unsigned char* __restrict__ npm,
    float* __restrict__ pacc,
    float* __restrict__ pm,
    float* __restrict__ pl)
{
    __shared__ unsigned short Kl[2][64 * 64];   // 8 KB each, swizzled rows
    __shared__ unsigned short Vl[2][64 * 64];   // 8 KB each, [kg][d][k8]
    __shared__ float maskF[1024];               // additive mask (f32)
    __shared__ int tmask[16];

    const int tid = threadIdx.x;
    const int l = tid & 63, w = tid >> 6;
    const int bh = blockIdx.x, b = bh >> 4;
    const int t0 = blockIdx.y * 64;
    const int half = blockIdx.z;

    const unsigned short* kb_ = half ? nkbf : kbf;   // [bh][1024][64] rows
    const unsigned short* vb_ = half ? nvtb : vtb;   // [bh][32][64][32] panels

    if (tid < 16) tmask[tid] = 0;
    __syncthreads();
    for (int s = tid; s < 1024; s += 256) {
        int masked;
        if (half == 0) masked = kpm[(size_t)b * N_ + s] ? 1 : 0;
        else           masked = (s < M_ && !npm[(size_t)b * M_ + s]) ? 0 : 1;
        maskF[s] = masked ? -60000.f : 0.f;
        if (masked) atomicOr(&tmask[s >> 6], 1);
    }

    // staging: 512 chunks each for K and V; thread handles chunks tid, 256+tid
    auto STAGE = [&](int buf, int s0) {
        #pragma unroll
        for (int u = 0; u < 2; ++u) {
            const int c = u * 256 + tid;
            const int krow = c >> 3;
            const int kcol = ((c & 7) * 16) ^ ((krow & 7) << 4);
            gload16((const unsigned char*)kb_ +
                        ((size_t)(bh * 1024 + s0 + krow) * 64) * 2 + kcol,
                    (unsigned char*)&Kl[buf][0] + c * 16);
            const int kg = c >> 6;
            const int dd = c & 63;
            const int kv = s0 + kg * 8;
            const int kp = kv >> 5;
            gload16((const unsigned char*)vb_ +
                        (((size_t)(bh * 32 + kp) * 64 + dd) * 32 + (kv & 31)) * 2,
                    (unsigned char*)&Vl[buf][0] + c * 16);
        }
    };

    const int g = l >> 4;
    const int q = l & 15;

    const int qrow = t0 + w * 16 + q;
    const short8 aq0 = *reinterpret_cast<const short8*>(&qbf[((size_t)bh * T_ + qrow) * 64 + g * 8]);
    const short8 aq1 = *reinterpret_cast<const short8*>(&qbf[((size_t)bh * T_ + qrow) * 64 + 32 + g * 8]);

    float mold = -30000.f, lr = 0.f;
    f32x4 acco[4];
    #pragma unroll
    for (int n = 0; n < 4; ++n) acco[n] = (f32x4){0.f, 0.f, 0.f, 0.f};

    // LDS fragment read offsets (bytes)
    const int ksw = (l & 7) << 4;
    const int kb0 = q * 128 + ((g * 16) ^ ksw);        // + n*2048
    const int kb1 = q * 128 + ((64 + g * 16) ^ ksw);   // + n*2048
    const int vb0 = g * 1024 + q * 16;                 // + n*256 (+4096 for half 1)

    // redistribution source lanes
    const int src0 = (g & 1) * 32 + q;   // words 0,1
    const int src1 = src0 + 16;          // words 2,3
    const bool selhi = (l & 32) != 0;    // g>>1: pick ppk[2h+1] half

    STAGE(0, 0);
    __syncthreads();    // drains vmcnt(0): buf0 staged; mask filled

    for (int it = 0; it < 16; ++it) {
        const int s0 = it * 64;
        const int cur = it & 1;
        if (it < 15) STAGE(cur ^ 1, s0 + 64);

        const unsigned char* const Kc = (const unsigned char*)&Kl[cur][0];
        const unsigned char* const Vc = (const unsigned char*)&Vl[cur][0];

        // ---- QK^T (swapped): accs[n][j] = S[q][k = n*16 + g*4 + j] ----
        f32x4 accs[4];
        #pragma unroll
        for (int n = 0; n < 4; ++n) accs[n] = (f32x4){0.f, 0.f, 0.f, 0.f};
        __builtin_amdgcn_s_setprio(1);
        #pragma unroll
        for (int n = 0; n < 4; ++n) {
            const short8 k0 = *reinterpret_cast<const short8*>(Kc + n * 2048 + kb0);
            const short8 k1 = *reinterpret_cast<const short8*>(Kc + n * 2048 + kb1);
            accs[n] = MFMA16(k0, aq0, accs[n]);
            accs[n] = MFMA16(k1, aq1, accs[n]);
        }
        __builtin_amdgcn_s_setprio(0);

        // ---- mask in-place (only if tile has any masked col) ----
        if (tmask[s0 >> 6]) {
            #pragma unroll
            for (int n = 0; n < 4; ++n) {
                const float4 mz = *reinterpret_cast<const float4*>(&maskF[s0 + n * 16 + g * 4]);
                accs[n][0] += mz.x;
                accs[n][1] += mz.y;
                accs[n][2] += mz.z;
                accs[n][3] += mz.w;
            }
        }

        // ---- row max: in-lane over 16, then cross-group xor16/xor32 ----
        float mx = -60000.f;
        #pragma unroll
        for (int n = 0; n < 4; ++n)
            #pragma unroll
            for (int j = 0; j < 4; ++j) mx = fmaxf(mx, accs[n][j]);
        mx = fmaxf(mx, __shfl_xor(mx, 16));
        mx = fmaxf(mx, __shfl_xor(mx, 32));

        // ---- defer-max ----
        if (__any(mx > mold + 8.f)) {
            const float mn = fmaxf(mold, mx);
            const float f = __builtin_amdgcn_exp2f(mold - mn);
            mold = mn;
            lr *= f;
            #pragma unroll
            for (int n = 0; n < 4; ++n)
                #pragma unroll
                for (int j = 0; j < 4; ++j) acco[n][j] *= f;
        }

        // ---- P = exp2(s - m) (fp32), row-sum, pack to bf16 pairs ----
        float p[4][4];
        float ps = 0.f;
        #pragma unroll
        for (int n = 0; n < 4; ++n)
            #pragma unroll
            for (int j = 0; j < 4; ++j) {
                p[n][j] = __builtin_amdgcn_exp2f(accs[n][j] - mold);
                ps += p[n][j];
            }
        ps += __shfl_xor(ps, 16);
        ps += __shfl_xor(ps, 32);
        lr += ps;

        unsigned int ppk[4][2];
        #pragma unroll
        for (int n = 0; n < 4; ++n) {
            ppk[n][0] = cvt_pk_bf16(p[n][0], p[n][1]);
            ppk[n][1] = cvt_pk_bf16(p[n][2], p[n][3]);
        }

        // ---- redistribute to P^T B-frags (16 shfl + 8 sel) ----
        union UF { int4 i4; short8 s8; } pf[2];
        #pragma unroll
        for (int h = 0; h < 2; ++h) {
            const unsigned int a0 = __shfl((int)ppk[2 * h][0],     src0);
            const unsigned int b0 = __shfl((int)ppk[2 * h + 1][0], src0);
            const unsigned int a1 = __shfl((int)ppk[2 * h][1],     src0);
            const unsigned int b1 = __shfl((int)ppk[2 * h + 1][1], src0);
            const unsigned int a2 = __shfl((int)ppk[2 * h][0],     src1);
            const unsigned int b2 = __shfl((int)ppk[2 * h + 1][0], src1);
            const unsigned int a3 = __shfl((int)ppk[2 * h][1],     src1);
            const unsigned int b3 = __shfl((int)ppk[2 * h + 1][1], src1);
            pf[h].i4.x = selhi ? b0 : a0;
            pf[h].i4.y = selhi ? b1 : a1;
            pf[h].i4.z = selhi ? b2 : a2;
            pf[h].i4.w = selhi ? b3 : a3;
        }

        // ---- PV: O^T = V^T . P^T  (V reads byte-identical to R6) ----
        __builtin_amdgcn_s_setprio(1);
        #pragma unroll
        for (int n = 0; n < 4; ++n) {
            const short8 v0 = *reinterpret_cast<const short8*>(Vc + n * 256 + vb0);
            const short8 v1 = *reinterpret_cast<const short8*>(Vc + 4096 + n * 256 + vb0);
            acco[n] = MFMA16(v0, pf[0].s8, acco[n]);
            acco[n] = MFMA16(v1, pf[1].s8, acco[n]);
        }
        __builtin_amdgcn_s_setprio(0);

        __syncthreads();    // next buf staged (vmcnt drained); cur free to reuse
    }

    // ---- epilogue: acco[n][j] = O[q][d = n*16 + g*4 + j] ----
    const size_t row = ((size_t)(half * 64 + bh)) * 1024 + t0 + w * 16 + q;
    #pragma unroll
    for (int n = 0; n < 4; ++n) {
        float4 st;
        st.x = acco[n][0];
        st.y = acco[n][1];
        st.z = acco[n][2];
        st.w = acco[n][3];
        *reinterpret_cast<float4*>(&pacc[row * 64 + n * 16 + g * 4]) = st;
    }
    if (l < 16) {
        pm[row] = mold;
        pl[row] = lr;
    }
}

// ---------------------------------------------------------------------------
// Merge the two S-halves: o = (a0*w0 + a1*w1) / (l0*w0 + l1*w1), w = 2^(m-m*).
// ---------------------------------------------------------------------------
__global__ void merge_kernel(const float* __restrict__ pacc,
                             const float* __restrict__ pm,
                             const float* __restrict__ pl,
                             unsigned short* __restrict__ ohi,
                             unsigned short* __restrict__ olo)
{
    const int g = blockIdx.x * 256 + threadIdx.x;
    const int row = g >> 4;              // bh*1024 + t
    const int d4 = (g & 15) * 4;
    const int bh = row >> 10, t = row & 1023;
    const int b = bh >> 4, h = bh & 15;

    const float m0 = pm[row], m1 = pm[65536 + row];
    const float l0 = pl[row], l1 = pl[65536 + row];
    const float ms = fmaxf(m0, m1);
    const float w0 = __builtin_amdgcn_exp2f(m0 - ms);
    const float w1 = __builtin_amdgcn_exp2f(m1 - ms);
    const float den = 1.f / (l0 * w0 + l1 * w1);

    const float4 a0 = *reinterpret_cast<const float4*>(&pacc[(size_t)row * 64 + d4]);
    const float4 a1 = *reinterpret_cast<const float4*>(&pacc[(size_t)(65536 + row) * 64 + d4]);

    float o[4] = {
        (a0.x * w0 + a1.x * w1) * den,
        (a0.y * w0 + a1.y * w1) * den,
        (a0.z * w0 + a1.z * w1) * den,
        (a0.w * w0 + a1.w * w1) * den,
    };
    ushort4 vh_, vl_;
    unsigned short hh[4], ll[4];
    #pragma unroll
    for (int k = 0; k < 4; ++k) {
        hh[k] = f2bf(o[k]);
        ll[k] = f2bf(o[k] - bf2f(hh[k]));
    }
    vh_.x = hh[0]; vh_.y = hh[1]; vh_.z = hh[2]; vh_.w = hh[3];
    vl_.x = ll[0]; vl_.y = ll[1]; vl_.z = ll[2]; vl_.w = ll[3];
    const size_t oidx = ((size_t)t * B_ + b) * E_ + h * D_ + d4;
    *reinterpret_cast<ushort4*>(&ohi[oidx]) = vh_;
    *reinterpret_cast<ushort4*>(&olo[oidx]) = vl_;
}

// ---------------------------------------------------------------------------
extern "C" void kernel_launch(void* const* d_in, const int* in_sizes, int n_in,
                              void* d_out, int out_size, void* d_ws, size_t ws_size,
                              hipStream_t stream) {
    const float* query    = (const float*)d_in[0];
    const float* key      = (const float*)d_in[1];
    const float* node_key = (const float*)d_in[2];
    const float* ipw      = (const float*)d_in[3];
    const float* ipb      = (const float*)d_in[4];
    const float* out_w    = (const float*)d_in[5];
    const float* out_b    = (const float*)d_in[6];
    const float* dw_w     = (const float*)d_in[7];
    const float* dw_b     = (const float*)d_in[8];
    const unsigned char* kpm = (const unsigned char*)d_in[9];
    const unsigned char* npm = (const unsigned char*)d_in[10];
    float* out = (float*)d_out;

    char* p = (char*)d_ws;
    auto alloc = [&](size_t bytes) {
        char* r = p;
        p += (bytes + 255) & ~(size_t)255;
        return r;
    };
    // xq..pad region (32 MiB) is reused as pacc after proj_mfma has consumed it
    unsigned short* xq    = (unsigned short*)alloc((size_t)4096 * 1024 * 2);
    unsigned short* xk    = (unsigned short*)alloc((size_t)4096 * 1024 * 2);
    unsigned short* xn    = (unsigned short*)alloc((size_t)4096 * 1024 * 2);
    unsigned short* wbf   = (unsigned short*)alloc((size_t)3072 * 1024 * 2);
    (void)alloc((size_t)2 * 1024 * 1024);   // pad so pacc (32 MiB) fits over xq..here
    unsigned short* wohi  = (unsigned short*)alloc((size_t)1024 * 1024 * 2);
    unsigned short* wolo  = (unsigned short*)alloc((size_t)1024 * 1024 * 2);
    unsigned short* qb    = (unsigned short*)alloc((size_t)64 * 1024 * 64 * 2);
    unsigned short* kb_   = (unsigned short*)alloc((size_t)64 * 1024 * 64 * 2);
    unsigned short* nkb   = (unsigned short*)alloc((size_t)64 * 1024 * 64 * 2);
    unsigned short* vtb   = (unsigned short*)alloc((size_t)64 * 1024 * 64 * 2);
    unsigned short* nvtb  = (unsigned short*)alloc((size_t)64 * 1024 * 64 * 2);
    unsigned short* ohi   = (unsigned short*)alloc((size_t)4096 * 1024 * 2);
    unsigned short* olo   = (unsigned short*)alloc((size_t)4096 * 1024 * 2);
    float*          dwb   = (float*)alloc((size_t)4096 * 16 * 4);
    float*          pm    = (float*)alloc((size_t)2 * 65536 * 4);
    float*          pl    = (float*)alloc((size_t)2 * 65536 * 4);
    float*          pacc  = (float*)xq;     // 2*64*1024*64 f32 = 32 MiB overlay

    const dim3 blk(256);

    // 1) conversions
    f2bf_kernel<<<dim3(4096), blk, 0, stream>>>(query,    xq, 4194304, 4194304);
    f2bf_kernel<<<dim3(4096), blk, 0, stream>>>(key,      xk, 4194304, 4194304);
    f2bf_kernel<<<dim3(4096), blk, 0, stream>>>(node_key, xn, 4190208, 4194304);
    f2bf_kernel<<<dim3(3072), blk, 0, stream>>>(ipw,      wbf, 3145728, 3145728);
    f2bf_hilo_kernel<<<dim3(1024), blk, 0, stream>>>(out_w, wohi, wolo, 1048576);

    // 2) dw gate
    dw_kernel<<<dim3(M_ * B_), blk, 0, stream>>>(node_key, dw_w, dw_b, dwb);

    // 3) fused input projections
    proj_mfma<<<dim3(8, 32, 5), blk, 0, stream>>>(xq, xk, xn, wbf, ipb, dwb,
                                                  qb, kb_, vtb, nkb, nvtb);

    // 4) attention, split-S, swapped QK^T (overwrites xq-region with pacc)
    attn_mfma<<<dim3(64, 16, 2), blk, 0, stream>>>(qb, kb_, nkb, vtb, nvtb,
                                                   kpm, npm, pacc, pm, pl);

    // 5) merge halves -> hi/lo bf16 o
    merge_kernel<<<dim3(4096), blk, 0, stream>>>(pacc, pm, pl, ohi, olo);

    // 6) output projection (hi/lo 3-term) -> d_out fp32
    outproj_mfma<<<dim3(8, 32), blk, 0, stream>>>(ohi, olo, wohi, wolo, out_b, out);
}

// Round 8
// 256.764 us; speedup vs baseline: 1.7710x; 1.0506x over previous
//
#include <hip/hip_runtime.h>
#include <cstdint>
#include <cstddef>

using short8 = __attribute__((ext_vector_type(8))) short;
using f32x4  = __attribute__((ext_vector_type(4))) float;

constexpr int T_ = 1024;
constexpr int N_ = 1024;
constexpr int M_ = 1023;
constexpr int B_ = 4;
constexpr int E_ = 1024;
constexpr int H_ = 16;
constexpr int D_ = 64;

#define MFMA16(a, b, c) __builtin_amdgcn_mfma_f32_16x16x32_bf16((a), (b), (c), 0, 0, 0)

__device__ __forceinline__ unsigned short f2bf(float f) {
    unsigned int u = __float_as_uint(f);
    u += 0x7FFF + ((u >> 16) & 1);          // round-to-nearest-even
    return (unsigned short)(u >> 16);
}
__device__ __forceinline__ float bf2f(unsigned short s) {
    return __uint_as_float(((unsigned int)s) << 16);
}

// HW packed fp32->bf16 pair conversion (RNE). lo -> bits[15:0], hi -> [31:16].
__device__ __forceinline__ unsigned int cvt_pk_bf16(float lo, float hi) {
    unsigned int r;
    asm("v_cvt_pk_bf16_f32 %0, %1, %2" : "=v"(r) : "v"(lo), "v"(hi));
    return r;
}

// global -> LDS direct copy, 16 B per lane. LDS dest must be wave-uniform;
// HW writes lds_base + lane*16. Global source IS per-lane -> swizzles are
// applied by permuting the SOURCE address (m173), LDS stays linear.
typedef __attribute__((address_space(1))) const unsigned char gc_byte;
typedef __attribute__((address_space(3))) unsigned char lds_byte;
__device__ __forceinline__ void gload16(const void* g, void* lds) {
    __builtin_amdgcn_global_load_lds((gc_byte*)(uintptr_t)g,
                                     (lds_byte*)(unsigned int)(uintptr_t)lds,
                                     16, 0, 0);
}

// ---------------------------------------------------------------------------
// fp32 -> bf16 conversion, with zero-padding from n..npad (npad % 4 == 0)
// ---------------------------------------------------------------------------
__global__ void f2bf_kernel(const float* __restrict__ src,
                            unsigned short* __restrict__ dst, int n, int npad)
{
    int i = (blockIdx.x * 256 + threadIdx.x) * 4;
    if (i >= npad) return;
    if (i + 4 <= n) {
        const float4 v = *reinterpret_cast<const float4*>(src + i);
        ushort4 o;
        o.x = f2bf(v.x); o.y = f2bf(v.y); o.z = f2bf(v.z); o.w = f2bf(v.w);
        *reinterpret_cast<ushort4*>(dst + i) = o;
    } else {
        for (int k = 0; k < 4; ++k)
            dst[i + k] = (i + k < n) ? f2bf(src[i + k]) : (unsigned short)0;
    }
}

// fp32 -> (bf16 hi, bf16 lo) split.  n % 4 == 0
__global__ void f2bf_hilo_kernel(const float* __restrict__ src,
                                 unsigned short* __restrict__ dhi,
                                 unsigned short* __restrict__ dlo, int n)
{
    int i = (blockIdx.x * 256 + threadIdx.x) * 4;
    if (i >= n) return;
    const float4 v = *reinterpret_cast<const float4*>(src + i);
    float a[4] = {v.x, v.y, v.z, v.w};
    ushort4 hi, lo;
    unsigned short h[4], l[4];
    #pragma unroll
    for (int k = 0; k < 4; ++k) {
        h[k] = f2bf(a[k]);
        l[k] = f2bf(a[k] - bf2f(h[k]));
    }
    hi.x = h[0]; hi.y = h[1]; hi.z = h[2]; hi.w = h[3];
    lo.x = l[0]; lo.y = l[1]; lo.z = l[2]; lo.w = l[3];
    *reinterpret_cast<ushort4*>(dhi + i) = hi;
    *reinterpret_cast<ushort4*>(dlo + i) = lo;
}

// ---------------------------------------------------------------------------
// dw gate kernel (fp32): dw[r*H+h] = sigmoid(node_key_r . dw_w[h] + dw_b[h])
// ---------------------------------------------------------------------------
__global__ void dw_kernel(const float* __restrict__ node_key,
                          const float* __restrict__ dw_w,
                          const float* __restrict__ dw_b,
                          float* __restrict__ dwb)
{
    __shared__ float rowbuf[E_];
    const int r = blockIdx.x;
    const int tid = threadIdx.x;
    for (int idx = tid; idx < E_; idx += 256)
        rowbuf[idx] = node_key[(size_t)r * E_ + idx];
    __syncthreads();
    const int h = tid >> 4;
    const int lane = tid & 15;
    float acc = 0.f;
    const float* wrow = dw_w + (size_t)h * E_;
    for (int k = lane; k < E_; k += 16)
        acc = fmaf(rowbuf[k], wrow[k], acc);
    acc += __shfl_xor(acc, 8);
    acc += __shfl_xor(acc, 4);
    acc += __shfl_xor(acc, 2);
    acc += __shfl_xor(acc, 1);
    if (lane == 0) {
        float x = acc + dw_b[h];
        dwb[(size_t)r * H_ + h] = 1.f / (1.f + __expf(-x));
    }
}

// ---------------------------------------------------------------------------
// Fused input projections, R8: triple-buffered counted-vmcnt pipeline (T4).
// Per iter: vmcnt(4) [waits only loads issued 2 iters ago] -> raw s_barrier
// -> issue STAGE(t+2) -> compute buf[t%3]. Loads for t+1/t+2 stay in flight
// across the barrier (never drain to 0 in the loop).
// Hazards: STAGE(t+2) writes buf[(t+2)%3], last read at iter t-1 -- fenced
// by this iter's top barrier (all waves past compute t-1). Cross-wave LDS
// visibility: per-wave vmcnt before barrier covers S_t (vmcnt tracks
// global_load_lds, m135).
// ---------------------------------------------------------------------------
__global__ __launch_bounds__(256) void proj_mfma(
    const unsigned short* __restrict__ xq,
    const unsigned short* __restrict__ xk,
    const unsigned short* __restrict__ xn,
    const unsigned short* __restrict__ wbf,
    const float* __restrict__ ipb,
    const float* __restrict__ dwb,
    unsigned short* __restrict__ qb,
    unsigned short* __restrict__ kb,
    unsigned short* __restrict__ vtb,
    unsigned short* __restrict__ nkb,
    unsigned short* __restrict__ nvtb)
{
    __shared__ unsigned short LDS[3][2][128 * 32];   // 48 KB, triple-buffered

    const unsigned short* A;
    const unsigned short* W;
    const float* bias;
    const float* dwm = nullptr;
    unsigned short* out;
    int epi;
    float scale = 1.f;
    switch (blockIdx.z) {
      case 0:  A = xq; W = wbf;           bias = ipb;        out = qb;   epi = 1; scale = 0.18033688011112042f; break;
      case 1:  A = xk; W = wbf + 1048576; bias = ipb + 1024; out = kb;   epi = 1; break;
      case 2:  A = xk; W = wbf + 2097152; bias = ipb + 2048; out = vtb;  epi = 2; break;
      case 3:  A = xn; W = wbf + 1048576; bias = ipb + 1024; out = nkb;  epi = 1; break;
      default: A = xn; W = wbf + 2097152; bias = ipb + 2048; out = nvtb; epi = 2; dwm = dwb; break;
    }

    const int tid = threadIdx.x;
    const int l = tid & 63, w = tid >> 6;
    const int brow = blockIdx.y * 128;
    const int bcol = blockIdx.x * 128;

    const int ch0 = w * 64 + l;
    const int ch1 = 256 + w * 64 + l;
    const unsigned short* gA0 = A + (size_t)(brow + (ch0 >> 2)) * E_ + (ch0 & 3) * 8;
    const unsigned short* gA1 = A + (size_t)(brow + (ch1 >> 2)) * E_ + (ch1 & 3) * 8;
    const unsigned short* gW0 = W + (size_t)(bcol + (ch0 >> 2)) * E_ + (ch0 & 3) * 8;
    const unsigned short* gW1 = W + (size_t)(bcol + (ch1 >> 2)) * E_ + (ch1 & 3) * 8;

    auto STAGE = [&](int buf, int kt) {
        gload16(gA0 + kt, &LDS[buf][0][(size_t)w * 512]);
        gload16(gA1 + kt, &LDS[buf][0][(size_t)(4 + w) * 512]);
        gload16(gW0 + kt, &LDS[buf][1][(size_t)w * 512]);
        gload16(gW1 + kt, &LDS[buf][1][(size_t)(4 + w) * 512]);
    };

    f32x4 acc[4][4];
    #pragma unroll
    for (int m = 0; m < 4; ++m)
        #pragma unroll
        for (int n = 0; n < 4; ++n)
            acc[m][n] = (f32x4){0.f, 0.f, 0.f, 0.f};

    const int wr = (w >> 1) * 64, wc = (w & 1) * 64;
    const int fr = l & 15, ko = (l >> 4) * 8;

    // prologue: 2 stages in flight
    STAGE(0, 0);
    STAGE(1, 32);

    for (int t = 0; t < 32; ++t) {
        // wait S_t complete (newest 4 loads = S_{t+1} may stay in flight)
        if (t < 31) asm volatile("s_waitcnt vmcnt(4)" ::: "memory");
        else        asm volatile("s_waitcnt vmcnt(0)" ::: "memory");
        __builtin_amdgcn_sched_barrier(0);
        __builtin_amdgcn_s_barrier();       // raw barrier: no vmcnt(0) drain
        __builtin_amdgcn_sched_barrier(0);

        if (t < 30) STAGE((t + 2) % 3, (t + 2) * 32);

        const int cur = t % 3;
        short8 av[4], bv[4];
        #pragma unroll
        for (int m = 0; m < 4; ++m)
            av[m] = *reinterpret_cast<const short8*>(&LDS[cur][0][(wr + m * 16 + fr) * 32 + ko]);
        #pragma unroll
        for (int n = 0; n < 4; ++n)
            bv[n] = *reinterpret_cast<const short8*>(&LDS[cur][1][(wc + n * 16 + fr) * 32 + ko]);
        __builtin_amdgcn_s_setprio(1);
        #pragma unroll
        for (int m = 0; m < 4; ++m)
            #pragma unroll
            for (int n = 0; n < 4; ++n)
                acc[m][n] = MFMA16(av[m], bv[n], acc[m][n]);
        __builtin_amdgcn_s_setprio(0);
    }

    #pragma unroll
    for (int n = 0; n < 4; ++n) {
        const int c = bcol + wc + n * 16 + fr;
        const float bi = bias[c];
        #pragma unroll
        for (int m = 0; m < 4; ++m) {
            #pragma unroll
            for (int j = 0; j < 4; ++j) {
                const int r = brow + wr + m * 16 + (l >> 4) * 4 + j;
                float v = (acc[m][n][j] + bi) * scale;
                const int rn = r >> 2, b = r & 3, hh = c >> 6, dd = c & 63;
                if (epi == 1) {
                    out[((size_t)(b * H_ + hh) * 1024 + rn) * 64 + dd] = f2bf(v);
                } else {
                    if (dwm) v *= dwm[(size_t)r * H_ + hh];
                    out[(((size_t)(b * H_ + hh) * 32 + (rn >> 5)) * 64 + dd) * 32 + (rn & 31)] = f2bf(v);
                }
            }
        }
    }
}

// ---------------------------------------------------------------------------
// Output projection, hi/lo 3-term (unchanged from R3).
// ---------------------------------------------------------------------------
__global__ __launch_bounds__(256) void outproj_mfma(
    const unsigned short* __restrict__ ahi,
    const unsigned short* __restrict__ alo,
    const unsigned short* __restrict__ whi,
    const unsigned short* __restrict__ wlo,
    const float* __restrict__ out_b,
    float* __restrict__ out)
{
    __shared__ unsigned short LDS[2][4][128 * 32];

    const int tid = threadIdx.x;
    const int l = tid & 63, w = tid >> 6;
    const int brow = blockIdx.y * 128;
    const int bcol = blockIdx.x * 128;

    const int ch0 = w * 64 + l;
    const int ch1 = 256 + w * 64 + l;
    const size_t ra0 = (size_t)(brow + (ch0 >> 2)) * E_ + (ch0 & 3) * 8;
    const size_t ra1 = (size_t)(brow + (ch1 >> 2)) * E_ + (ch1 & 3) * 8;
    const size_t rb0 = (size_t)(bcol + (ch0 >> 2)) * E_ + (ch0 & 3) * 8;
    const size_t rb1 = (size_t)(bcol + (ch1 >> 2)) * E_ + (ch1 & 3) * 8;

    auto STAGE = [&](int buf, int kt) {
        gload16(ahi + ra0 + kt, &LDS[buf][0][(size_t)w * 512]);
        gload16(ahi + ra1 + kt, &LDS[buf][0][(size_t)(4 + w) * 512]);
        gload16(alo + ra0 + kt, &LDS[buf][1][(size_t)w * 512]);
        gload16(alo + ra1 + kt, &LDS[buf][1][(size_t)(4 + w) * 512]);
        gload16(whi + rb0 + kt, &LDS[buf][2][(size_t)w * 512]);
        gload16(whi + rb1 + kt, &LDS[buf][2][(size_t)(4 + w) * 512]);
        gload16(wlo + rb0 + kt, &LDS[buf][3][(size_t)w * 512]);
        gload16(wlo + rb1 + kt, &LDS[buf][3][(size_t)(4 + w) * 512]);
    };

    f32x4 acc[4][4];
    #pragma unroll
    for (int m = 0; m < 4; ++m)
        #pragma unroll
        for (int n = 0; n < 4; ++n)
            acc[m][n] = (f32x4){0.f, 0.f, 0.f, 0.f};

    const int wr = (w >> 1) * 64, wc = (w & 1) * 64;
    const int fr = l & 15, ko = (l >> 4) * 8;

    STAGE(0, 0);
    __syncthreads();
    for (int t = 0; t < 32; ++t) {
        const int cur = t & 1;
        if (t < 31) STAGE(cur ^ 1, (t + 1) * 32);
        short8 ah[4], al[4], bh[4], bl[4];
        #pragma unroll
        for (int m = 0; m < 4; ++m) {
            ah[m] = *reinterpret_cast<const short8*>(&LDS[cur][0][(wr + m * 16 + fr) * 32 + ko]);
            al[m] = *reinterpret_cast<const short8*>(&LDS[cur][1][(wr + m * 16 + fr) * 32 + ko]);
        }
        #pragma unroll
        for (int n = 0; n < 4; ++n) {
            bh[n] = *reinterpret_cast<const short8*>(&LDS[cur][2][(wc + n * 16 + fr) * 32 + ko]);
            bl[n] = *reinterpret_cast<const short8*>(&LDS[cur][3][(wc + n * 16 + fr) * 32 + ko]);
        }
        #pragma unroll
        for (int m = 0; m < 4; ++m)
            #pragma unroll
            for (int n = 0; n < 4; ++n) {
                acc[m][n] = MFMA16(ah[m], bh[n], acc[m][n]);
                acc[m][n] = MFMA16(al[m], bh[n], acc[m][n]);
                acc[m][n] = MFMA16(ah[m], bl[n], acc[m][n]);
            }
        if (t < 31) __syncthreads();
    }

    #pragma unroll
    for (int n = 0; n < 4; ++n) {
        const int c = bcol + wc + n * 16 + fr;
        const float bi = out_b[c];
        #pragma unroll
        for (int m = 0; m < 4; ++m)
            #pragma unroll
            for (int j = 0; j < 4; ++j) {
                const int r = brow + wr + m * 16 + (l >> 4) * 4 + j;
                out[(size_t)r * E_ + c] = acc[m][n][j] + bi;
            }
    }
}

// ---------------------------------------------------------------------------
// MFMA flash attention, SPLIT-S, LDS-staged K/V, SWAPPED QK^T (unchanged R7).
// ---------------------------------------------------------------------------
__global__ __launch_bounds__(256) void attn_mfma(
    const unsigned short* __restrict__ qbf,
    const unsigned short* __restrict__ kbf,
    const unsigned short* __restrict__ nkbf,
    const unsigned short* __restrict__ vtb,
    const unsigned short* __restrict__ nvtb,
    const unsigned char* __restrict__ kpm,
    const unsigned char* __restrict__ npm,
    float* __restrict__ pacc,
    float* __restrict__ pm,
    float* __restrict__ pl)
{
    __shared__ unsigned short Kl[2][64 * 64];   // 8 KB each, swizzled rows
    __shared__ unsigned short Vl[2][64 * 64];   // 8 KB each, [kg][d][k8]
    __shared__ float maskF[1024];               // additive mask (f32)
    __shared__ int tmask[16];

    const int tid = threadIdx.x;
    const int l = tid & 63, w = tid >> 6;
    const int bh = blockIdx.x, b = bh >> 4;
    const int t0 = blockIdx.y * 64;
    const int half = blockIdx.z;

    const unsigned short* kb_ = half ? nkbf : kbf;   // [bh][1024][64] rows
    const unsigned short* vb_ = half ? nvtb : vtb;   // [bh][32][64][32] panels

    if (tid < 16) tmask[tid] = 0;
    __syncthreads();
    for (int s = tid; s < 1024; s += 256) {
        int masked;
        if (half == 0) masked = kpm[(size_t)b * N_ + s] ? 1 : 0;
        else           masked = (s < M_ && !npm[(size_t)b * M_ + s]) ? 0 : 1;
        maskF[s] = masked ? -60000.f : 0.f;
        if (masked) atomicOr(&tmask[s >> 6], 1);
    }

    // staging: 512 chunks each for K and V; thread handles chunks tid, 256+tid
    auto STAGE = [&](int buf, int s0) {
        #pragma unroll
        for (int u = 0; u < 2; ++u) {
            const int c = u * 256 + tid;
            const int krow = c >> 3;
            const int kcol = ((c & 7) * 16) ^ ((krow & 7) << 4);
            gload16((const unsigned char*)kb_ +
                        ((size_t)(bh * 1024 + s0 + krow) * 64) * 2 + kcol,
                    (unsigned char*)&Kl[buf][0] + c * 16);
            const int kg = c >> 6;
            const int dd = c & 63;
            const int kv = s0 + kg * 8;
            const int kp = kv >> 5;
            gload16((const unsigned char*)vb_ +
                        (((size_t)(bh * 32 + kp) * 64 + dd) * 32 + (kv & 31)) * 2,
                    (unsigned char*)&Vl[buf][0] + c * 16);
        }
    };

    const int g = l >> 4;
    const int q = l & 15;

    const int qrow = t0 + w * 16 + q;
    const short8 aq0 = *reinterpret_cast<const short8*>(&qbf[((size_t)bh * T_ + qrow) * 64 + g * 8]);
    const short8 aq1 = *reinterpret_cast<const short8*>(&qbf[((size_t)bh * T_ + qrow) * 64 + 32 + g * 8]);

    float mold = -30000.f, lr = 0.f;
    f32x4 acco[4];
    #pragma unroll
    for (int n = 0; n < 4; ++n) acco[n] = (f32x4){0.f, 0.f, 0.f, 0.f};

    // LDS fragment read offsets (bytes)
    const int ksw = (l & 7) << 4;
    const int kb0 = q * 128 + ((g * 16) ^ ksw);        // + n*2048
    const int kb1 = q * 128 + ((64 + g * 16) ^ ksw);   // + n*2048
    const int vb0 = g * 1024 + q * 16;                 // + n*256 (+4096 for half 1)

    // redistribution source lanes
    const int src0 = (g & 1) * 32 + q;   // words 0,1
    const int src1 = src0 + 16;          // words 2,3
    const bool selhi = (l & 32) != 0;    // g>>1: pick ppk[2h+1] half

    STAGE(0, 0);
    __syncthreads();    // drains vmcnt(0): buf0 staged; mask filled

    for (int it = 0; it < 16; ++it) {
        const int s0 = it * 64;
        const int cur = it & 1;
        if (it < 15) STAGE(cur ^ 1, s0 + 64);

        const unsigned char* const Kc = (const unsigned char*)&Kl[cur][0];
        const unsigned char* const Vc = (const unsigned char*)&Vl[cur][0];

        // ---- QK^T (swapped): accs[n][j] = S[q][k = n*16 + g*4 + j] ----
        f32x4 accs[4];
        #pragma unroll
        for (int n = 0; n < 4; ++n) accs[n] = (f32x4){0.f, 0.f, 0.f, 0.f};
        __builtin_amdgcn_s_setprio(1);
        #pragma unroll
        for (int n = 0; n < 4; ++n) {
            const short8 k0 = *reinterpret_cast<const short8*>(Kc + n * 2048 + kb0);
            const short8 k1 = *reinterpret_cast<const short8*>(Kc + n * 2048 + kb1);
            accs[n] = MFMA16(k0, aq0, accs[n]);
            accs[n] = MFMA16(k1, aq1, accs[n]);
        }
        __builtin_amdgcn_s_setprio(0);

        // ---- mask in-place (only if tile has any masked col) ----
        if (tmask[s0 >> 6]) {
            #pragma unroll
            for (int n = 0; n < 4; ++n) {
                const float4 mz = *reinterpret_cast<const float4*>(&maskF[s0 + n * 16 + g * 4]);
                accs[n][0] += mz.x;
                accs[n][1] += mz.y;
                accs[n][2] += mz.z;
                accs[n][3] += mz.w;
            }
        }

        // ---- row max: in-lane over 16, then cross-group xor16/xor32 ----
        float mx = -60000.f;
        #pragma unroll
        for (int n = 0; n < 4; ++n)
            #pragma unroll
            for (int j = 0; j < 4; ++j) mx = fmaxf(mx, accs[n][j]);
        mx = fmaxf(mx, __shfl_xor(mx, 16));
        mx = fmaxf(mx, __shfl_xor(mx, 32));

        // ---- defer-max ----
        if (__any(mx > mold + 8.f)) {
            const float mn = fmaxf(mold, mx);
            const float f = __builtin_amdgcn_exp2f(mold - mn);
            mold = mn;
            lr *= f;
            #pragma unroll
            for (int n = 0; n < 4; ++n)
                #pragma unroll
                for (int j = 0; j < 4; ++j) acco[n][j] *= f;
        }

        // ---- P = exp2(s - m) (fp32), row-sum, pack to bf16 pairs ----
        float p[4][4];
        float ps = 0.f;
        #pragma unroll
        for (int n = 0; n < 4; ++n)
            #pragma unroll
            for (int j = 0; j < 4; ++j) {
                p[n][j] = __builtin_amdgcn_exp2f(accs[n][j] - mold);
                ps += p[n][j];
            }
        ps += __shfl_xor(ps, 16);
        ps += __shfl_xor(ps, 32);
        lr += ps;

        unsigned int ppk[4][2];
        #pragma unroll
        for (int n = 0; n < 4; ++n) {
            ppk[n][0] = cvt_pk_bf16(p[n][0], p[n][1]);
            ppk[n][1] = cvt_pk_bf16(p[n][2], p[n][3]);
        }

        // ---- redistribute to P^T B-frags (16 shfl + 8 sel) ----
        union UF { int4 i4; short8 s8; } pf[2];
        #pragma unroll
        for (int h = 0; h < 2; ++h) {
            const unsigned int a0 = __shfl((int)ppk[2 * h][0],     src0);
            const unsigned int b0 = __shfl((int)ppk[2 * h + 1][0], src0);
            const unsigned int a1 = __shfl((int)ppk[2 * h][1],     src0);
            const unsigned int b1 = __shfl((int)ppk[2 * h + 1][1], src0);
            const unsigned int a2 = __shfl((int)ppk[2 * h][0],     src1);
            const unsigned int b2 = __shfl((int)ppk[2 * h + 1][0], src1);
            const unsigned int a3 = __shfl((int)ppk[2 * h][1],     src1);
            const unsigned int b3 = __shfl((int)ppk[2 * h + 1][1], src1);
            pf[h].i4.x = selhi ? b0 : a0;
            pf[h].i4.y = selhi ? b1 : a1;
            pf[h].i4.z = selhi ? b2 : a2;
            pf[h].i4.w = selhi ? b3 : a3;
        }

        // ---- PV: O^T = V^T . P^T  (V reads byte-identical to R6) ----
        __builtin_amdgcn_s_setprio(1);
        #pragma unroll
        for (int n = 0; n < 4; ++n) {
            const short8 v0 = *reinterpret_cast<const short8*>(Vc + n * 256 + vb0);
            const short8 v1 = *reinterpret_cast<const short8*>(Vc + 4096 + n * 256 + vb0);
            acco[n] = MFMA16(v0, pf[0].s8, acco[n]);
            acco[n] = MFMA16(v1, pf[1].s8, acco[n]);
        }
        __builtin_amdgcn_s_setprio(0);

        __syncthreads();    // next buf staged (vmcnt drained); cur free to reuse
    }

    // ---- epilogue: acco[n][j] = O[q][d = n*16 + g*4 + j] ----
    const size_t row = ((size_t)(half * 64 + bh)) * 1024 + t0 + w * 16 + q;
    #pragma unroll
    for (int n = 0; n < 4; ++n) {
        float4 st;
        st.x = acco[n][0];
        st.y = acco[n][1];
        st.z = acco[n][2];
        st.w = acco[n][3];
        *reinterpret_cast<float4*>(&pacc[row * 64 + n * 16 + g * 4]) = st;
    }
    if (l < 16) {
        pm[row] = mold;
        pl[row] = lr;
    }
}

// ---------------------------------------------------------------------------
// Merge the two S-halves: o = (a0*w0 + a1*w1) / (l0*w0 + l1*w1), w = 2^(m-m*).
// ---------------------------------------------------------------------------
__global__ void merge_kernel(const float* __restrict__ pacc,
                             const float* __restrict__ pm,
                             const float* __restrict__ pl,
                             unsigned short* __restrict__ ohi,
                             unsigned short* __restrict__ olo)
{
    const int g = blockIdx.x * 256 + threadIdx.x;
    const int row = g >> 4;              // bh*1024 + t
    const int d4 = (g & 15) * 4;
    const int bh = row >> 10, t = row & 1023;
    const int b = bh >> 4, h = bh & 15;

    const float m0 = pm[row], m1 = pm[65536 + row];
    const float l0 = pl[row], l1 = pl[65536 + row];
    const float ms = fmaxf(m0, m1);
    const float w0 = __builtin_amdgcn_exp2f(m0 - ms);
    const float w1 = __builtin_amdgcn_exp2f(m1 - ms);
    const float den = 1.f / (l0 * w0 + l1 * w1);

    const float4 a0 = *reinterpret_cast<const float4*>(&pacc[(size_t)row * 64 + d4]);
    const float4 a1 = *reinterpret_cast<const float4*>(&pacc[(size_t)(65536 + row) * 64 + d4]);

    float o[4] = {
        (a0.x * w0 + a1.x * w1) * den,
        (a0.y * w0 + a1.y * w1) * den,
        (a0.z * w0 + a1.z * w1) * den,
        (a0.w * w0 + a1.w * w1) * den,
    };
    ushort4 vh_, vl_;
    unsigned short hh[4], ll[4];
    #pragma unroll
    for (int k = 0; k < 4; ++k) {
        hh[k] = f2bf(o[k]);
        ll[k] = f2bf(o[k] - bf2f(hh[k]));
    }
    vh_.x = hh[0]; vh_.y = hh[1]; vh_.z = hh[2]; vh_.w = hh[3];
    vl_.x = ll[0]; vl_.y = ll[1]; vl_.z = ll[2]; vl_.w = ll[3];
    const size_t oidx = ((size_t)t * B_ + b) * E_ + h * D_ + d4;
    *reinterpret_cast<ushort4*>(&ohi[oidx]) = vh_;
    *reinterpret_cast<ushort4*>(&olo[oidx]) = vl_;
}

// ---------------------------------------------------------------------------
extern "C" void kernel_launch(void* const* d_in, const int* in_sizes, int n_in,
                              void* d_out, int out_size, void* d_ws, size_t ws_size,
                              hipStream_t stream) {
    const float* query    = (const float*)d_in[0];
    const float* key      = (const float*)d_in[1];
    const float* node_key = (const float*)d_in[2];
    const float* ipw      = (const float*)d_in[3];
    const float* ipb      = (const float*)d_in[4];
    const float* out_w    = (const float*)d_in[5];
    const float* out_b    = (const float*)d_in[6];
    const float* dw_w     = (const float*)d_in[7];
    const float* dw_b     = (const float*)d_in[8];
    const unsigned char* kpm = (const unsigned char*)d_in[9];
    const unsigned char* npm = (const unsigned char*)d_in[10];
    float* out = (float*)d_out;

    char* p = (char*)d_ws;
    auto alloc = [&](size_t bytes) {
        char* r = p;
        p += (bytes + 255) & ~(size_t)255;
        return r;
    };
    // xq..pad region (32 MiB) is reused as pacc after proj_mfma has consumed it
    unsigned short* xq    = (unsigned short*)alloc((size_t)4096 * 1024 * 2);
    unsigned short* xk    = (unsigned short*)alloc((size_t)4096 * 1024 * 2);
    unsigned short* xn    = (unsigned short*)alloc((size_t)4096 * 1024 * 2);
    unsigned short* wbf   = (unsigned short*)alloc((size_t)3072 * 1024 * 2);
    (void)alloc((size_t)2 * 1024 * 1024);   // pad so pacc (32 MiB) fits over xq..here
    unsigned short* wohi  = (unsigned short*)alloc((size_t)1024 * 1024 * 2);
    unsigned short* wolo  = (unsigned short*)alloc((size_t)1024 * 1024 * 2);
    unsigned short* qb    = (unsigned short*)alloc((size_t)64 * 1024 * 64 * 2);
    unsigned short* kb_   = (unsigned short*)alloc((size_t)64 * 1024 * 64 * 2);
    unsigned short* nkb   = (unsigned short*)alloc((size_t)64 * 1024 * 64 * 2);
    unsigned short* vtb   = (unsigned short*)alloc((size_t)64 * 1024 * 64 * 2);
    unsigned short* nvtb  = (unsigned short*)alloc((size_t)64 * 1024 * 64 * 2);
    unsigned short* ohi   = (unsigned short*)alloc((size_t)4096 * 1024 * 2);
    unsigned short* olo   = (unsigned short*)alloc((size_t)4096 * 1024 * 2);
    float*          dwb   = (float*)alloc((size_t)4096 * 16 * 4);
    float*          pm    = (float*)alloc((size_t)2 * 65536 * 4);
    float*          pl    = (float*)alloc((size_t)2 * 65536 * 4);
    float*          pacc  = (float*)xq;     // 2*64*1024*64 f32 = 32 MiB overlay

    const dim3 blk(256);

    // 1) conversions
    f2bf_kernel<<<dim3(4096), blk, 0, stream>>>(query,    xq, 4194304, 4194304);
    f2bf_kernel<<<dim3(4096), blk, 0, stream>>>(key,      xk, 4194304, 4194304);
    f2bf_kernel<<<dim3(4096), blk, 0, stream>>>(node_key, xn, 4190208, 4194304);
    f2bf_kernel<<<dim3(3072), blk, 0, stream>>>(ipw,      wbf, 3145728, 3145728);
    f2bf_hilo_kernel<<<dim3(1024), blk, 0, stream>>>(out_w, wohi, wolo, 1048576);

    // 2) dw gate
    dw_kernel<<<dim3(M_ * B_), blk, 0, stream>>>(node_key, dw_w, dw_b, dwb);

    // 3) fused input projections (counted-vmcnt pipeline)
    proj_mfma<<<dim3(8, 32, 5), blk, 0, stream>>>(xq, xk, xn, wbf, ipb, dwb,
                                                  qb, kb_, vtb, nkb, nvtb);

    // 4) attention, split-S, swapped QK^T (overwrites xq-region with pacc)
    attn_mfma<<<dim3(64, 16, 2), blk, 0, stream>>>(qb, kb_, nkb, vtb, nvtb,
                                                   kpm, npm, pacc, pm, pl);

    // 5) merge halves -> hi/lo bf16 o
    merge_kernel<<<dim3(4096), blk, 0, stream>>>(pacc, pm, pl, ohi, olo);

    // 6) output projection (hi/lo 3-term) -> d_out fp32
    outproj_mfma<<<dim3(8, 32), blk, 0, stream>>>(ohi, olo, wohi, wolo, out_b, out);
}